// Round 1
// baseline (1494.440 us; speedup 1.0000x reference)
//
#include <hip/hip_runtime.h>

// Problem constants (verified against in_sizes at launch where cheap).
#define DFEAT 64            // feature dim
#define WPAD 132            // LDS row stride for W (64 rows x 128 cols, pad +4 floats)

// ---------------------------------------------------------------------------
// Kernel 1: edge scatter.  16 lanes per edge, each lane one float4.
//   agg[dst[e]*64 + c*4 .. +3] += feature[src[e]*64 + c*4 .. +3]
// ---------------------------------------------------------------------------
__global__ __launch_bounds__(256) void gcn_scatter_kernel(
    const float4* __restrict__ feat4,   // [N][16] float4 view of feature
    const int* __restrict__ src,
    const int* __restrict__ dst,
    float* __restrict__ agg,            // [N][64], pre-zeroed
    int n_edges) {
  long long gid = (long long)blockIdx.x * blockDim.x + threadIdx.x;
  int e = (int)(gid >> 4);
  int c = (int)(gid & 15);
  if (e >= n_edges) return;
  int s = src[e];
  int d = dst[e];
  float4 v = feat4[(long long)s * 16 + c];
  float* p = agg + (long long)d * DFEAT + c * 4;
  atomicAdd(p + 0, v.x);
  atomicAdd(p + 1, v.y);
  atomicAdd(p + 2, v.z);
  atomicAdd(p + 3, v.w);
}

// ---------------------------------------------------------------------------
// Kernel 2: fused concat + Linear.
//   out[n][j] = sum_k feature[n][k]*W[j][k] + sum_k agg[n][k]*W[j][64+k] + b[j]
// Block = 256 threads = 4 waves; block handles 16 nodes (4 per wave).
// Lane j (0..63) computes output column j.  W staged in LDS with stride 132
// (lanes 0..7 cover all 32 banks for ds_read_b128 -> conflict-free).
// h rows staged in LDS, read as wave-broadcast (free).
// Safe when agg aliases out: all agg reads for this block's nodes happen
// before any out write (staging + __syncthreads).
// ---------------------------------------------------------------------------
__global__ __launch_bounds__(256) void gcn_gemm_kernel(
    const float* __restrict__ feat,   // [N][64]
    const float* __restrict__ agg,    // [N][64]
    const float* __restrict__ W,      // [64][128] row-major
    const float* __restrict__ bias,   // [64]
    float* __restrict__ out,          // [N][64]
    int n_nodes) {
  __shared__ float Wl[64 * WPAD];     // 33792 B
  __shared__ float hl[16][128];       // 8192 B
  int tid = threadIdx.x;

  // Stage W: 64x128 floats = 2048 float4s, 256 threads -> 8 iters, coalesced.
  for (int i = tid; i < 64 * 32; i += 256) {
    int j  = i >> 5;    // row 0..63
    int k4 = i & 31;    // float4 index 0..31
    float4 w = ((const float4*)W)[i];
    *((float4*)&Wl[j * WPAD + k4 * 4]) = w;
  }

  int node0 = blockIdx.x * 16;
  // Stage h = [feature | agg] for 16 nodes. 256 float4 per half, 1 iter each.
  {
    int m  = tid >> 4;   // node 0..15
    int k4 = tid & 15;   // float4 0..15 within 64 floats
    int n = node0 + m;
    if (n < n_nodes) {
      float4 f = ((const float4*)feat)[(long long)n * 16 + k4];
      *((float4*)&hl[m][k4 * 4]) = f;
      float4 a = ((const float4*)agg)[(long long)n * 16 + k4];
      *((float4*)&hl[m][64 + k4 * 4]) = a;
    }
  }
  __syncthreads();

  int wave = tid >> 6;       // 0..3
  int lane = tid & 63;       // output column j
  int mbase = wave * 4;      // 4 nodes per wave

  float acc0 = 0.f, acc1 = 0.f, acc2 = 0.f, acc3 = 0.f;
#pragma unroll
  for (int k4 = 0; k4 < 32; ++k4) {
    float4 w = *((const float4*)&Wl[lane * WPAD + k4 * 4]);
    float4 h0 = *((const float4*)&hl[mbase + 0][k4 * 4]);
    float4 h1 = *((const float4*)&hl[mbase + 1][k4 * 4]);
    float4 h2 = *((const float4*)&hl[mbase + 2][k4 * 4]);
    float4 h3 = *((const float4*)&hl[mbase + 3][k4 * 4]);
    acc0 += w.x * h0.x + w.y * h0.y + w.z * h0.z + w.w * h0.w;
    acc1 += w.x * h1.x + w.y * h1.y + w.z * h1.z + w.w * h1.w;
    acc2 += w.x * h2.x + w.y * h2.y + w.z * h2.z + w.w * h2.w;
    acc3 += w.x * h3.x + w.y * h3.y + w.z * h3.z + w.w * h3.w;
  }

  float bj = bias[lane];
  int n = node0 + mbase;
  if (n + 0 < n_nodes) out[(long long)(n + 0) * DFEAT + lane] = acc0 + bj;
  if (n + 1 < n_nodes) out[(long long)(n + 1) * DFEAT + lane] = acc1 + bj;
  if (n + 2 < n_nodes) out[(long long)(n + 2) * DFEAT + lane] = acc2 + bj;
  if (n + 3 < n_nodes) out[(long long)(n + 3) * DFEAT + lane] = acc3 + bj;
}

extern "C" void kernel_launch(void* const* d_in, const int* in_sizes, int n_in,
                              void* d_out, int out_size, void* d_ws, size_t ws_size,
                              hipStream_t stream) {
  const float* feat = (const float*)d_in[0];
  const int*   src  = (const int*)d_in[1];
  const int*   dst  = (const int*)d_in[2];
  const float* W    = (const float*)d_in[3];
  const float* bias = (const float*)d_in[4];
  float* out = (float*)d_out;

  int n_nodes = in_sizes[0] / DFEAT;   // 100000
  int n_edges = in_sizes[1];           // 1600000

  size_t agg_bytes = (size_t)n_nodes * DFEAT * sizeof(float);
  // agg lives in workspace if it fits; else alias onto out (safe: gemm stages
  // agg rows for its nodes into LDS before writing those nodes' outputs).
  float* agg = (ws_size >= agg_bytes) ? (float*)d_ws : out;

  hipMemsetAsync(agg, 0, agg_bytes, stream);

  long long scatter_threads = (long long)n_edges * 16;
  int scatter_blocks = (int)((scatter_threads + 255) / 256);
  gcn_scatter_kernel<<<scatter_blocks, 256, 0, stream>>>(
      (const float4*)feat, src, dst, agg, n_edges);

  int gemm_blocks = (n_nodes + 15) / 16;
  gcn_gemm_kernel<<<gemm_blocks, 256, 0, stream>>>(
      feat, agg, W, bias, out, n_nodes);
}

// Round 2
// 1201.849 us; speedup vs baseline: 1.2435x; 1.2435x over previous
//
#include <hip/hip_runtime.h>

#define DFEAT 64
#define SCAN_CHUNK 512
#define NODES_PER_BLOCK 16

// ===========================================================================
// CSR-build kernels
// ===========================================================================

__global__ __launch_bounds__(256) void gcn_hist(
    const int* __restrict__ dst, int* __restrict__ deg, int n_edges) {
  int e = blockIdx.x * 256 + threadIdx.x;
  if (e < n_edges) atomicAdd(&deg[dst[e]], 1);
}

// Per-chunk inclusive scan (Hillis-Steele in LDS). offsets[gi+1] = local
// inclusive sum; partials[b] = chunk total.
__global__ __launch_bounds__(SCAN_CHUNK) void gcn_scan_block(
    const int* __restrict__ deg, int* __restrict__ offsets,
    int* __restrict__ partials, int n) {
  __shared__ int buf[2][SCAN_CHUNK];
  int t = threadIdx.x;
  int gi = blockIdx.x * SCAN_CHUNK + t;
  int v = (gi < n) ? deg[gi] : 0;
  buf[0][t] = v;
  __syncthreads();
  int pin = 0;
  for (int s = 1; s < SCAN_CHUNK; s <<= 1) {
    int pout = pin ^ 1;
    int val = buf[pin][t];
    if (t >= s) val += buf[pin][t - s];
    buf[pout][t] = val;
    __syncthreads();
    pin = pout;
  }
  if (gi < n) offsets[gi + 1] = buf[pin][t];
  if (t == SCAN_CHUNK - 1) partials[blockIdx.x] = buf[pin][t];
}

// Exclusive scan of chunk totals (nchunks <= 1024), serial in LDS.
__global__ __launch_bounds__(256) void gcn_scan_partials(
    int* __restrict__ partials, int nchunks) {
  __shared__ int buf[1024];
  int t = threadIdx.x;
  for (int i = t; i < nchunks; i += 256) buf[i] = partials[i];
  __syncthreads();
  if (t == 0) {
    int run = 0;
    for (int i = 0; i < nchunks; ++i) { int v = buf[i]; buf[i] = run; run += v; }
  }
  __syncthreads();
  for (int i = t; i < nchunks; i += 256) partials[i] = buf[i];
}

__global__ __launch_bounds__(SCAN_CHUNK) void gcn_scan_add(
    int* __restrict__ offsets, const int* __restrict__ partials, int n) {
  int gi = blockIdx.x * SCAN_CHUNK + threadIdx.x;
  if (gi < n) offsets[gi + 1] += partials[blockIdx.x];
  if (gi == 0) offsets[0] = 0;
}

__global__ __launch_bounds__(256) void gcn_fill(
    const int* __restrict__ src, const int* __restrict__ dst,
    int* __restrict__ cursor, int* __restrict__ edge_src, int n_edges) {
  int e = blockIdx.x * 256 + threadIdx.x;
  if (e >= n_edges) return;
  int pos = atomicAdd(&cursor[dst[e]], 1);
  edge_src[pos] = src[e];
}

// ===========================================================================
// Fused gather + concat + Linear.
// Block = 256 threads = 4 waves; 16 nodes/block (4 per wave).
// Gather: lane k accumulates agg[k] for the wave's 4 nodes (4-way ILP over
// independent CSR chains); coalesced 256B reads of L3-resident feature.
// GEMM: W staged as XOR-swizzled float4 tile (conflict-free stage + read,
// 32KB exactly); h rows in LDS read via wave-broadcast.
// LDS total = 40KB -> 4 blocks/CU.
// ===========================================================================
__global__ __launch_bounds__(256) void gcn_gather_gemm(
    const float* __restrict__ feat,      // [N][64]
    const int* __restrict__ edge_src,    // CSR src ids, grouped by dst
    const int* __restrict__ offsets,     // [N+1]
    const float* __restrict__ W,         // [64][128]
    const float* __restrict__ bias,      // [64]
    float* __restrict__ out,             // [N][64]
    int n_nodes) {
  __shared__ float4 Wl4[2048];                       // 32 KB, swizzled
  __shared__ __align__(16) float hl[NODES_PER_BLOCK][128];  // 8 KB
  int tid = threadIdx.x;

  // Stage W: global read coalesced; LDS write conflict-free via XOR swizzle.
  for (int i = tid; i < 2048; i += 256) {
    int j = i >> 5, k4 = i & 31;
    Wl4[k4 * 64 + (j ^ (k4 & 7))] = ((const float4*)W)[i];
  }

  int node0 = blockIdx.x * NODES_PER_BLOCK;
  int wave = tid >> 6, lane = tid & 63;
  int mbase = wave * 4;

  // --- gather: 4 nodes per wave, interleaved for ILP ---
  float acc[4] = {0.f, 0.f, 0.f, 0.f};
  int off[4], dg[4];
#pragma unroll
  for (int r = 0; r < 4; ++r) {
    int n = node0 + mbase + r;
    if (n < n_nodes) { off[r] = offsets[n]; dg[r] = offsets[n + 1] - off[r]; }
    else             { off[r] = 0; dg[r] = 0; }
  }
  int maxd = max(max(dg[0], dg[1]), max(dg[2], dg[3]));
  for (int i = 0; i < maxd; ++i) {
#pragma unroll
    for (int r = 0; r < 4; ++r) {
      if (i < dg[r]) {
        int s = edge_src[off[r] + i];          // wave-uniform -> broadcast
        acc[r] += feat[s * DFEAT + lane];      // coalesced 256B/wave
      }
    }
  }

#pragma unroll
  for (int r = 0; r < 4; ++r) {
    int n = node0 + mbase + r;
    if (n < n_nodes) {
      hl[mbase + r][lane]      = feat[n * DFEAT + lane];
      hl[mbase + r][64 + lane] = acc[r];
    }
  }
  __syncthreads();

  // --- GEMM: lane = output column j; 4 nodes per wave ---
  float a0 = 0.f, a1 = 0.f, a2 = 0.f, a3 = 0.f;
#pragma unroll
  for (int k4 = 0; k4 < 32; ++k4) {
    float4 w  = Wl4[k4 * 64 + (lane ^ (k4 & 7))];
    float4 h0 = *((const float4*)&hl[mbase + 0][k4 * 4]);
    float4 h1 = *((const float4*)&hl[mbase + 1][k4 * 4]);
    float4 h2 = *((const float4*)&hl[mbase + 2][k4 * 4]);
    float4 h3 = *((const float4*)&hl[mbase + 3][k4 * 4]);
    a0 += w.x * h0.x + w.y * h0.y + w.z * h0.z + w.w * h0.w;
    a1 += w.x * h1.x + w.y * h1.y + w.z * h1.z + w.w * h1.w;
    a2 += w.x * h2.x + w.y * h2.y + w.z * h2.z + w.w * h2.w;
    a3 += w.x * h3.x + w.y * h3.y + w.z * h3.z + w.w * h3.w;
  }

  float bj = bias[lane];
  int n = node0 + mbase;
  if (n + 0 < n_nodes) out[(n + 0) * DFEAT + lane] = a0 + bj;
  if (n + 1 < n_nodes) out[(n + 1) * DFEAT + lane] = a1 + bj;
  if (n + 2 < n_nodes) out[(n + 2) * DFEAT + lane] = a2 + bj;
  if (n + 3 < n_nodes) out[(n + 3) * DFEAT + lane] = a3 + bj;
}

// ===========================================================================
// Fallback path (round-1): atomic scatter + separate GEMM, used only if the
// workspace is too small for the CSR buffers.
// ===========================================================================
__global__ __launch_bounds__(256) void gcn_scatter_kernel(
    const float4* __restrict__ feat4, const int* __restrict__ src,
    const int* __restrict__ dst, float* __restrict__ agg, int n_edges) {
  long long gid = (long long)blockIdx.x * blockDim.x + threadIdx.x;
  int e = (int)(gid >> 4);
  int c = (int)(gid & 15);
  if (e >= n_edges) return;
  float4 v = feat4[src[e] * 16 + c];
  float* p = agg + dst[e] * DFEAT + c * 4;
  atomicAdd(p + 0, v.x);
  atomicAdd(p + 1, v.y);
  atomicAdd(p + 2, v.z);
  atomicAdd(p + 3, v.w);
}

__global__ __launch_bounds__(256) void gcn_gemm_kernel(
    const float* __restrict__ feat, const float* __restrict__ agg,
    const float* __restrict__ W, const float* __restrict__ bias,
    float* __restrict__ out, int n_nodes) {
  __shared__ float4 Wl4[2048];
  __shared__ __align__(16) float hl[NODES_PER_BLOCK][128];
  int tid = threadIdx.x;
  for (int i = tid; i < 2048; i += 256) {
    int j = i >> 5, k4 = i & 31;
    Wl4[k4 * 64 + (j ^ (k4 & 7))] = ((const float4*)W)[i];
  }
  int node0 = blockIdx.x * NODES_PER_BLOCK;
  int wave = tid >> 6, lane = tid & 63;
  int mbase = wave * 4;
#pragma unroll
  for (int r = 0; r < 4; ++r) {
    int n = node0 + mbase + r;
    if (n < n_nodes) {
      hl[mbase + r][lane]      = feat[n * DFEAT + lane];
      hl[mbase + r][64 + lane] = agg[n * DFEAT + lane];
    }
  }
  __syncthreads();
  float a0 = 0.f, a1 = 0.f, a2 = 0.f, a3 = 0.f;
#pragma unroll
  for (int k4 = 0; k4 < 32; ++k4) {
    float4 w  = Wl4[k4 * 64 + (lane ^ (k4 & 7))];
    float4 h0 = *((const float4*)&hl[mbase + 0][k4 * 4]);
    float4 h1 = *((const float4*)&hl[mbase + 1][k4 * 4]);
    float4 h2 = *((const float4*)&hl[mbase + 2][k4 * 4]);
    float4 h3 = *((const float4*)&hl[mbase + 3][k4 * 4]);
    a0 += w.x * h0.x + w.y * h0.y + w.z * h0.z + w.w * h0.w;
    a1 += w.x * h1.x + w.y * h1.y + w.z * h1.z + w.w * h1.w;
    a2 += w.x * h2.x + w.y * h2.y + w.z * h2.z + w.w * h2.w;
    a3 += w.x * h3.x + w.y * h3.y + w.z * h3.z + w.w * h3.w;
  }
  float bj = bias[lane];
  int n = node0 + mbase;
  if (n + 0 < n_nodes) out[(n + 0) * DFEAT + lane] = a0 + bj;
  if (n + 1 < n_nodes) out[(n + 1) * DFEAT + lane] = a1 + bj;
  if (n + 2 < n_nodes) out[(n + 2) * DFEAT + lane] = a2 + bj;
  if (n + 3 < n_nodes) out[(n + 3) * DFEAT + lane] = a3 + bj;
}

// ===========================================================================

extern "C" void kernel_launch(void* const* d_in, const int* in_sizes, int n_in,
                              void* d_out, int out_size, void* d_ws, size_t ws_size,
                              hipStream_t stream) {
  const float* feat = (const float*)d_in[0];
  const int*   src  = (const int*)d_in[1];
  const int*   dst  = (const int*)d_in[2];
  const float* W    = (const float*)d_in[3];
  const float* bias = (const float*)d_in[4];
  float* out = (float*)d_out;

  int n_nodes = in_sizes[0] / DFEAT;   // 100000
  int n_edges = in_sizes[1];           // 1600000
  int nchunks = (n_nodes + SCAN_CHUNK - 1) / SCAN_CHUNK;   // 196

  // Workspace layout (all int32, 256B-aligned slabs)
  auto align_up = [](size_t x) { return (x + 255) & ~(size_t)255; };
  size_t deg_b     = align_up((size_t)n_nodes * 4);
  size_t off_b     = align_up((size_t)(n_nodes + 1) * 4);
  size_t cur_b     = align_up((size_t)n_nodes * 4);
  size_t part_b    = align_up((size_t)nchunks * 4);
  size_t esrc_b    = align_up((size_t)n_edges * 4);
  size_t need      = deg_b + off_b + cur_b + part_b + esrc_b;

  if (ws_size >= need && nchunks <= 1024) {
    char* p = (char*)d_ws;
    int* deg      = (int*)p;               p += deg_b;
    int* offsets  = (int*)p;               p += off_b;
    int* cursor   = (int*)p;               p += cur_b;
    int* partials = (int*)p;               p += part_b;
    int* edge_src = (int*)p;

    hipMemsetAsync(deg, 0, (size_t)n_nodes * 4, stream);

    int eblocks = (n_edges + 255) / 256;
    gcn_hist<<<eblocks, 256, 0, stream>>>(dst, deg, n_edges);
    gcn_scan_block<<<nchunks, SCAN_CHUNK, 0, stream>>>(deg, offsets, partials, n_nodes);
    gcn_scan_partials<<<1, 256, 0, stream>>>(partials, nchunks);
    gcn_scan_add<<<nchunks, SCAN_CHUNK, 0, stream>>>(offsets, partials, n_nodes);
    hipMemcpyAsync(cursor, offsets, (size_t)n_nodes * 4,
                   hipMemcpyDeviceToDevice, stream);
    gcn_fill<<<eblocks, 256, 0, stream>>>(src, dst, cursor, edge_src, n_edges);

    int gblocks = (n_nodes + NODES_PER_BLOCK - 1) / NODES_PER_BLOCK;
    gcn_gather_gemm<<<gblocks, 256, 0, stream>>>(
        feat, edge_src, offsets, W, bias, out, n_nodes);
  } else {
    // Fallback: atomic scatter path.
    size_t agg_bytes = (size_t)n_nodes * DFEAT * sizeof(float);
    float* agg = (ws_size >= agg_bytes) ? (float*)d_ws : out;
    hipMemsetAsync(agg, 0, agg_bytes, stream);
    long long st = (long long)n_edges * 16;
    gcn_scatter_kernel<<<(int)((st + 255) / 256), 256, 0, stream>>>(
        (const float4*)feat, src, dst, agg, n_edges);
    int gblocks = (n_nodes + NODES_PER_BLOCK - 1) / NODES_PER_BLOCK;
    gcn_gemm_kernel<<<gblocks, 256, 0, stream>>>(feat, agg, W, bias, out, n_nodes);
  }
}

// Round 3
// 335.948 us; speedup vs baseline: 4.4484x; 3.5775x over previous
//
#include <hip/hip_runtime.h>

#define DFEAT 64
#define SCAN_CHUNK 512
#define NODES_PER_BLOCK 16

// ===========================================================================
// CSR-build kernels
// ===========================================================================

__global__ __launch_bounds__(256) void gcn_hist(
    const int* __restrict__ dst, int* __restrict__ deg, int n_edges) {
  int e = blockIdx.x * 256 + threadIdx.x;
  if (e < n_edges) atomicAdd(&deg[dst[e]], 1);
}

// Per-chunk inclusive scan (Hillis-Steele in LDS). offsets[gi+1] = local
// inclusive sum; partials[b] = chunk total.
__global__ __launch_bounds__(SCAN_CHUNK) void gcn_scan_block(
    const int* __restrict__ deg, int* __restrict__ offsets,
    int* __restrict__ partials, int n) {
  __shared__ int buf[2][SCAN_CHUNK];
  int t = threadIdx.x;
  int gi = blockIdx.x * SCAN_CHUNK + t;
  int v = (gi < n) ? deg[gi] : 0;
  buf[0][t] = v;
  __syncthreads();
  int pin = 0;
  for (int s = 1; s < SCAN_CHUNK; s <<= 1) {
    int pout = pin ^ 1;
    int val = buf[pin][t];
    if (t >= s) val += buf[pin][t - s];
    buf[pout][t] = val;
    __syncthreads();
    pin = pout;
  }
  if (gi < n) offsets[gi + 1] = buf[pin][t];
  if (t == SCAN_CHUNK - 1) partials[blockIdx.x] = buf[pin][t];
}

// Exclusive scan of chunk totals (nchunks <= 1024), serial in LDS.
__global__ __launch_bounds__(256) void gcn_scan_partials(
    int* __restrict__ partials, int nchunks) {
  __shared__ int buf[1024];
  int t = threadIdx.x;
  for (int i = t; i < nchunks; i += 256) buf[i] = partials[i];
  __syncthreads();
  if (t == 0) {
    int run = 0;
    for (int i = 0; i < nchunks; ++i) { int v = buf[i]; buf[i] = run; run += v; }
  }
  __syncthreads();
  for (int i = t; i < nchunks; i += 256) partials[i] = buf[i];
}

__global__ __launch_bounds__(SCAN_CHUNK) void gcn_scan_add(
    int* __restrict__ offsets, const int* __restrict__ partials, int n) {
  int gi = blockIdx.x * SCAN_CHUNK + threadIdx.x;
  if (gi < n) offsets[gi + 1] += partials[blockIdx.x];
  if (gi == 0) offsets[0] = 0;
}

__global__ __launch_bounds__(256) void gcn_fill(
    const int* __restrict__ src, const int* __restrict__ dst,
    int* __restrict__ cursor, int* __restrict__ edge_src, int n_edges) {
  int e = blockIdx.x * 256 + threadIdx.x;
  if (e >= n_edges) return;
  int pos = atomicAdd(&cursor[dst[e]], 1);
  edge_src[pos] = src[e];
}

// ===========================================================================
// Fused gather + concat + Linear.
//
// Grid-stride over 16-node tiles; W staged once per block (32KB, XOR-swizzled
// float4 -> conflict-free stage and read).  LDS total 40KB -> 4 blocks/CU.
//
// Gather: one node per wave at a time.  Edge ids for the node are loaded 64
// at a time with ONE coalesced load into a register, then broadcast via
// __shfl; the 8-way-unrolled feat gathers are mutually independent -> many
// loads in flight (breaks the load->load latency chain that dominated r2).
// lane = feature index; acc[lane] = agg[n][lane].
//
// GEMM: lane = output column j; 4 nodes per wave; unroll capped to keep
// VGPR <= 128 (__launch_bounds__(256,4)).
// ===========================================================================
__global__ __launch_bounds__(256, 4) void gcn_gather_gemm(
    const float* __restrict__ feat,      // [N][64]
    const int* __restrict__ edge_src,    // CSR src ids, grouped by dst
    const int* __restrict__ offsets,     // [N+1]
    const float* __restrict__ W,         // [64][128]
    const float* __restrict__ bias,      // [64]
    float* __restrict__ out,             // [N][64]
    int n_nodes) {
  __shared__ float4 Wl4[2048];                              // 32 KB, swizzled
  __shared__ __align__(16) float hl[NODES_PER_BLOCK][128];  // 8 KB
  int tid = threadIdx.x;
  int wave = tid >> 6, lane = tid & 63;
  int mbase = wave * 4;

  // Stage W once per block.
  for (int i = tid; i < 2048; i += 256) {
    int j = i >> 5, k4 = i & 31;
    Wl4[k4 * 64 + (j ^ (k4 & 7))] = ((const float4*)W)[i];
  }

  float bj = bias[lane];

  for (int node0 = blockIdx.x * NODES_PER_BLOCK;
       node0 < n_nodes;
       node0 += gridDim.x * NODES_PER_BLOCK) {

    // --- gather: one node per wave at a time, batched ids + MLP ---
    for (int r = 0; r < 4; ++r) {
      int n = node0 + mbase + r;
      if (n >= n_nodes) break;
      int off = offsets[n];
      int deg = offsets[n + 1] - off;
      float a0 = 0.f, a1 = 0.f, a2 = 0.f, a3 = 0.f;
      for (int base = 0; base < deg; base += 64) {
        int cnt = min(64, deg - base);
        int id = (base + lane < deg) ? edge_src[off + base + lane] : 0;
        int j = 0;
        for (; j + 8 <= cnt; j += 8) {
          int s0 = __shfl(id, j + 0), s1 = __shfl(id, j + 1);
          int s2 = __shfl(id, j + 2), s3 = __shfl(id, j + 3);
          int s4 = __shfl(id, j + 4), s5 = __shfl(id, j + 5);
          int s6 = __shfl(id, j + 6), s7 = __shfl(id, j + 7);
          float f0 = feat[s0 * DFEAT + lane];
          float f1 = feat[s1 * DFEAT + lane];
          float f2 = feat[s2 * DFEAT + lane];
          float f3 = feat[s3 * DFEAT + lane];
          float f4 = feat[s4 * DFEAT + lane];
          float f5 = feat[s5 * DFEAT + lane];
          float f6 = feat[s6 * DFEAT + lane];
          float f7 = feat[s7 * DFEAT + lane];
          a0 += f0; a1 += f1; a2 += f2; a3 += f3;
          a0 += f4; a1 += f5; a2 += f6; a3 += f7;
        }
        for (; j < cnt; ++j) {
          int s = __shfl(id, j);
          a0 += feat[s * DFEAT + lane];
        }
      }
      hl[mbase + r][lane]      = feat[n * DFEAT + lane];
      hl[mbase + r][64 + lane] = (a0 + a1) + (a2 + a3);
    }
    __syncthreads();

    // --- GEMM: lane = output column j; 4 nodes per wave ---
    float c0 = 0.f, c1 = 0.f, c2 = 0.f, c3 = 0.f;
#pragma unroll 4
    for (int k4 = 0; k4 < 32; ++k4) {
      float4 w  = Wl4[k4 * 64 + (lane ^ (k4 & 7))];
      float4 h0 = *((const float4*)&hl[mbase + 0][k4 * 4]);
      float4 h1 = *((const float4*)&hl[mbase + 1][k4 * 4]);
      float4 h2 = *((const float4*)&hl[mbase + 2][k4 * 4]);
      float4 h3 = *((const float4*)&hl[mbase + 3][k4 * 4]);
      c0 += w.x * h0.x + w.y * h0.y + w.z * h0.z + w.w * h0.w;
      c1 += w.x * h1.x + w.y * h1.y + w.z * h1.z + w.w * h1.w;
      c2 += w.x * h2.x + w.y * h2.y + w.z * h2.z + w.w * h2.w;
      c3 += w.x * h3.x + w.y * h3.y + w.z * h3.z + w.w * h3.w;
    }

    int n = node0 + mbase;
    if (n + 0 < n_nodes) out[(n + 0) * DFEAT + lane] = c0 + bj;
    if (n + 1 < n_nodes) out[(n + 1) * DFEAT + lane] = c1 + bj;
    if (n + 2 < n_nodes) out[(n + 2) * DFEAT + lane] = c2 + bj;
    if (n + 3 < n_nodes) out[(n + 3) * DFEAT + lane] = c3 + bj;
    __syncthreads();   // hl reused next tile
  }
}

// ===========================================================================
// Fallback path: atomic scatter + separate GEMM, used only if the workspace
// is too small for the CSR buffers.
// ===========================================================================
__global__ __launch_bounds__(256) void gcn_scatter_kernel(
    const float4* __restrict__ feat4, const int* __restrict__ src,
    const int* __restrict__ dst, float* __restrict__ agg, int n_edges) {
  long long gid = (long long)blockIdx.x * blockDim.x + threadIdx.x;
  int e = (int)(gid >> 4);
  int c = (int)(gid & 15);
  if (e >= n_edges) return;
  float4 v = feat4[src[e] * 16 + c];
  float* p = agg + dst[e] * DFEAT + c * 4;
  atomicAdd(p + 0, v.x);
  atomicAdd(p + 1, v.y);
  atomicAdd(p + 2, v.z);
  atomicAdd(p + 3, v.w);
}

__global__ __launch_bounds__(256) void gcn_gemm_kernel(
    const float* __restrict__ feat, const float* __restrict__ agg,
    const float* __restrict__ W, const float* __restrict__ bias,
    float* __restrict__ out, int n_nodes) {
  __shared__ float4 Wl4[2048];
  __shared__ __align__(16) float hl[NODES_PER_BLOCK][128];
  int tid = threadIdx.x;
  for (int i = tid; i < 2048; i += 256) {
    int j = i >> 5, k4 = i & 31;
    Wl4[k4 * 64 + (j ^ (k4 & 7))] = ((const float4*)W)[i];
  }
  int node0 = blockIdx.x * NODES_PER_BLOCK;
  int wave = tid >> 6, lane = tid & 63;
  int mbase = wave * 4;
#pragma unroll
  for (int r = 0; r < 4; ++r) {
    int n = node0 + mbase + r;
    if (n < n_nodes) {
      hl[mbase + r][lane]      = feat[n * DFEAT + lane];
      hl[mbase + r][64 + lane] = agg[n * DFEAT + lane];
    }
  }
  __syncthreads();
  float a0 = 0.f, a1 = 0.f, a2 = 0.f, a3 = 0.f;
#pragma unroll 4
  for (int k4 = 0; k4 < 32; ++k4) {
    float4 w  = Wl4[k4 * 64 + (lane ^ (k4 & 7))];
    float4 h0 = *((const float4*)&hl[mbase + 0][k4 * 4]);
    float4 h1 = *((const float4*)&hl[mbase + 1][k4 * 4]);
    float4 h2 = *((const float4*)&hl[mbase + 2][k4 * 4]);
    float4 h3 = *((const float4*)&hl[mbase + 3][k4 * 4]);
    a0 += w.x * h0.x + w.y * h0.y + w.z * h0.z + w.w * h0.w;
    a1 += w.x * h1.x + w.y * h1.y + w.z * h1.z + w.w * h1.w;
    a2 += w.x * h2.x + w.y * h2.y + w.z * h2.z + w.w * h2.w;
    a3 += w.x * h3.x + w.y * h3.y + w.z * h3.z + w.w * h3.w;
  }
  float bj = bias[lane];
  int n = node0 + mbase;
  if (n + 0 < n_nodes) out[(n + 0) * DFEAT + lane] = a0 + bj;
  if (n + 1 < n_nodes) out[(n + 1) * DFEAT + lane] = a1 + bj;
  if (n + 2 < n_nodes) out[(n + 2) * DFEAT + lane] = a2 + bj;
  if (n + 3 < n_nodes) out[(n + 3) * DFEAT + lane] = a3 + bj;
}

// ===========================================================================

extern "C" void kernel_launch(void* const* d_in, const int* in_sizes, int n_in,
                              void* d_out, int out_size, void* d_ws, size_t ws_size,
                              hipStream_t stream) {
  const float* feat = (const float*)d_in[0];
  const int*   src  = (const int*)d_in[1];
  const int*   dst  = (const int*)d_in[2];
  const float* W    = (const float*)d_in[3];
  const float* bias = (const float*)d_in[4];
  float* out = (float*)d_out;

  int n_nodes = in_sizes[0] / DFEAT;   // 100000
  int n_edges = in_sizes[1];           // 1600000
  int nchunks = (n_nodes + SCAN_CHUNK - 1) / SCAN_CHUNK;   // 196

  // Workspace layout (all int32, 256B-aligned slabs)
  auto align_up = [](size_t x) { return (x + 255) & ~(size_t)255; };
  size_t deg_b     = align_up((size_t)n_nodes * 4);
  size_t off_b     = align_up((size_t)(n_nodes + 1) * 4);
  size_t cur_b     = align_up((size_t)n_nodes * 4);
  size_t part_b    = align_up((size_t)nchunks * 4);
  size_t esrc_b    = align_up((size_t)n_edges * 4);
  size_t need      = deg_b + off_b + cur_b + part_b + esrc_b;

  if (ws_size >= need && nchunks <= 1024) {
    char* p = (char*)d_ws;
    int* deg      = (int*)p;               p += deg_b;
    int* offsets  = (int*)p;               p += off_b;
    int* cursor   = (int*)p;               p += cur_b;
    int* partials = (int*)p;               p += part_b;
    int* edge_src = (int*)p;

    hipMemsetAsync(deg, 0, (size_t)n_nodes * 4, stream);

    int eblocks = (n_edges + 255) / 256;
    gcn_hist<<<eblocks, 256, 0, stream>>>(dst, deg, n_edges);
    gcn_scan_block<<<nchunks, SCAN_CHUNK, 0, stream>>>(deg, offsets, partials, n_nodes);
    gcn_scan_partials<<<1, 256, 0, stream>>>(partials, nchunks);
    gcn_scan_add<<<nchunks, SCAN_CHUNK, 0, stream>>>(offsets, partials, n_nodes);
    hipMemcpyAsync(cursor, offsets, (size_t)n_nodes * 4,
                   hipMemcpyDeviceToDevice, stream);
    gcn_fill<<<eblocks, 256, 0, stream>>>(src, dst, cursor, edge_src, n_edges);

    int ntiles = (n_nodes + NODES_PER_BLOCK - 1) / NODES_PER_BLOCK;
    int gblocks = ntiles < 2048 ? ntiles : 2048;
    gcn_gather_gemm<<<gblocks, 256, 0, stream>>>(
        feat, edge_src, offsets, W, bias, out, n_nodes);
  } else {
    // Fallback: atomic scatter path.
    size_t agg_bytes = (size_t)n_nodes * DFEAT * sizeof(float);
    float* agg = (ws_size >= agg_bytes) ? (float*)d_ws : out;
    hipMemsetAsync(agg, 0, agg_bytes, stream);
    long long st = (long long)n_edges * 16;
    gcn_scatter_kernel<<<(int)((st + 255) / 256), 256, 0, stream>>>(
        (const float4*)feat, src, dst, agg, n_edges);
    int gblocks = (n_nodes + NODES_PER_BLOCK - 1) / NODES_PER_BLOCK;
    gcn_gemm_kernel<<<gblocks, 256, 0, stream>>>(feat, agg, W, bias, out, n_nodes);
  }
}

// Round 4
// 172.750 us; speedup vs baseline: 8.6509x; 1.9447x over previous
//
#include <hip/hip_runtime.h>

#define DFEAT 64
#define NODES_PER_BLOCK 16
#define BKSZ 512            // nodes per bucket
#define SB 9                // log2(BKSZ)
#define MAXBKT 1024
#define PLACE_CHUNK 4096

__device__ inline unsigned short f2bf(float f) {
  unsigned int x = __float_as_uint(f);
  return (unsigned short)((x + 0x7fffu + ((x >> 16) & 1u)) >> 16);
}
__device__ inline float bf2f(unsigned short u) {
  return __uint_as_float(((unsigned int)u) << 16);
}

// ===========================================================================
// feat (fp32) -> bf16 table
// ===========================================================================
__global__ __launch_bounds__(256) void gcn_tobf16(
    const float4* __restrict__ feat4, ushort4* __restrict__ gb4, int n4) {
  int i = blockIdx.x * 256 + threadIdx.x;
  if (i >= n4) return;
  float4 f = feat4[i];
  ushort4 u;
  u.x = f2bf(f.x); u.y = f2bf(f.y); u.z = f2bf(f.z); u.w = f2bf(f.w);
  gb4[i] = u;
}

// ===========================================================================
// Bucketed counting sort (replaces hist+scan+fill):
//   bcount: per-bucket edge counts (LDS hist + one flush per block)
//   bscan : exclusive scan of bucket counts -> bbase, bcur
//   bplace: group (src,dst) pairs by bucket; block-reserved contiguous ranges
//   bfill : one block per bucket: degree count -> LDS scan -> offsets[] +
//           cursor placement of edge_src.  All scattered traffic confined to
//           a single-XCD 33KB window -> no line thrash.
// ===========================================================================
__global__ __launch_bounds__(256) void gcn_bcount(
    const int* __restrict__ dst, int* __restrict__ bcnt,
    int n_edges, int nbkt) {
  __shared__ int h[MAXBKT];
  for (int i = threadIdx.x; i < nbkt; i += 256) h[i] = 0;
  __syncthreads();
  for (int e = blockIdx.x * 256 + threadIdx.x; e < n_edges;
       e += gridDim.x * 256)
    atomicAdd(&h[dst[e] >> SB], 1);
  __syncthreads();
  for (int i = threadIdx.x; i < nbkt; i += 256)
    if (h[i]) atomicAdd(&bcnt[i], h[i]);
}

__global__ __launch_bounds__(1024) void gcn_bscan(
    const int* __restrict__ bcnt, int* __restrict__ bbase,
    int* __restrict__ bcur, int nbkt) {
  __shared__ int buf[2][1024];
  int t = threadIdx.x;
  int v = (t < nbkt) ? bcnt[t] : 0;
  buf[0][t] = v;
  __syncthreads();
  int pin = 0;
  for (int s = 1; s < 1024; s <<= 1) {
    int po = pin ^ 1;
    int val = buf[pin][t];
    if (t >= s) val += buf[pin][t - s];
    buf[po][t] = val;
    __syncthreads();
    pin = po;
  }
  if (t < nbkt) {
    int excl = (t == 0) ? 0 : buf[pin][t - 1];
    bbase[t] = excl;
    bcur[t] = excl;
    if (t == nbkt - 1) bbase[nbkt] = buf[pin][t];
  }
}

__global__ __launch_bounds__(256) void gcn_bplace(
    const int* __restrict__ src, const int* __restrict__ dst,
    int* __restrict__ bcur, int2* __restrict__ pairs,
    int n_edges, int nbkt) {
  __shared__ int cnt[MAXBKT];
  __shared__ int base[MAXBKT];
  int t = threadIdx.x;
  int e0 = blockIdx.x * PLACE_CHUNK;
  int e1 = min(e0 + PLACE_CHUNK, n_edges);
  for (int i = t; i < nbkt; i += 256) cnt[i] = 0;
  __syncthreads();
  for (int e = e0 + t; e < e1; e += 256)
    atomicAdd(&cnt[dst[e] >> SB], 1);
  __syncthreads();
  for (int i = t; i < nbkt; i += 256) {
    int c = cnt[i];
    base[i] = c ? atomicAdd(&bcur[i], c) : 0;
    cnt[i] = 0;   // reuse as local cursor
  }
  __syncthreads();
  for (int e = e0 + t; e < e1; e += 256) {
    int d = dst[e];
    int b = d >> SB;
    int pos = base[b] + atomicAdd(&cnt[b], 1);
    pairs[pos] = make_int2(src[e], d);
  }
}

__global__ __launch_bounds__(512) void gcn_bfill(
    const int2* __restrict__ pairs, const int* __restrict__ bbase,
    int* __restrict__ offsets, int* __restrict__ edge_src,
    int n_nodes, int n_edges, int nbkt) {
  __shared__ int deg[BKSZ];
  __shared__ int buf[2][BKSZ];
  __shared__ int cur[BKSZ];
  int b = blockIdx.x;
  int t = threadIdx.x;
  int n0 = b << SB;
  int e0 = bbase[b], e1 = bbase[b + 1];
  deg[t] = 0;
  __syncthreads();
  for (int e = e0 + t; e < e1; e += 512)
    atomicAdd(&deg[pairs[e].y - n0], 1);
  __syncthreads();
  buf[0][t] = deg[t];
  __syncthreads();
  int pin = 0;
  for (int s = 1; s < BKSZ; s <<= 1) {
    int po = pin ^ 1;
    int v = buf[pin][t];
    if (t >= s) v += buf[pin][t - s];
    buf[po][t] = v;
    __syncthreads();
    pin = po;
  }
  int excl = (t == 0) ? 0 : buf[pin][t - 1];
  cur[t] = excl;
  int n = n0 + t;
  if (n < n_nodes) offsets[n] = e0 + excl;
  if (b == nbkt - 1 && t == 0) offsets[n_nodes] = n_edges;
  __syncthreads();
  for (int e = e0 + t; e < e1; e += 512) {
    int2 p = pairs[e];
    int pos = atomicAdd(&cur[p.y - n0], 1);
    edge_src[e0 + pos] = p.x;
  }
}

// ===========================================================================
// Fused gather + concat + Linear.  BF16=1: gather from bf16 table, 2 edges
// per wave (lane = 32*half + k, each lane reads ushort2 -> 4x fewer VMEM
// instrs, 2x fewer bytes).  BF16=0: r3-style fp32 gather.
// ===========================================================================
template <int BF16>
__global__ __launch_bounds__(256, 4) void gcn_gather_gemm(
    const float* __restrict__ feat,          // [N][64] fp32
    const unsigned short* __restrict__ gb,   // [N][64] bf16 (BF16=1)
    const int* __restrict__ edge_src,
    const int* __restrict__ offsets,
    const float* __restrict__ W,             // [64][128]
    const float* __restrict__ bias,          // [64]
    float* __restrict__ out,                 // [N][64]
    int n_nodes) {
  __shared__ float4 Wl4[2048];                              // 32 KB swizzled
  __shared__ __align__(16) float hl[NODES_PER_BLOCK][128];  // 8 KB
  int tid = threadIdx.x;
  int wave = tid >> 6, lane = tid & 63;
  int mbase = wave * 4;
  int half = lane >> 5, kk = lane & 31;
  const ushort2* gb2 = (const ushort2*)gb;

  for (int i = tid; i < 2048; i += 256) {
    int j = i >> 5, k4 = i & 31;
    Wl4[k4 * 64 + (j ^ (k4 & 7))] = ((const float4*)W)[i];
  }
  float bj = bias[lane];

  for (int node0 = blockIdx.x * NODES_PER_BLOCK;
       node0 < n_nodes;
       node0 += gridDim.x * NODES_PER_BLOCK) {

    for (int r = 0; r < 4; ++r) {
      int n = node0 + mbase + r;
      if (n >= n_nodes) break;
      int off = offsets[n];
      int deg = offsets[n + 1] - off;

      if (BF16) {
        float2 a0 = {0.f, 0.f}, a1 = {0.f, 0.f};
        float2 a2 = {0.f, 0.f}, a3 = {0.f, 0.f};
        for (int base = 0; base < deg; base += 64) {
          int cnt = min(64, deg - base);
          int id = (base + lane < deg) ? edge_src[off + base + lane] : 0;
          int j = 0;
          for (; j + 8 <= cnt; j += 8) {
            int s0 = __shfl(id, j + half);
            int s1 = __shfl(id, j + 2 + half);
            int s2 = __shfl(id, j + 4 + half);
            int s3 = __shfl(id, j + 6 + half);
            ushort2 u0 = gb2[s0 * 32 + kk];
            ushort2 u1 = gb2[s1 * 32 + kk];
            ushort2 u2 = gb2[s2 * 32 + kk];
            ushort2 u3 = gb2[s3 * 32 + kk];
            a0.x += bf2f(u0.x); a0.y += bf2f(u0.y);
            a1.x += bf2f(u1.x); a1.y += bf2f(u1.y);
            a2.x += bf2f(u2.x); a2.y += bf2f(u2.y);
            a3.x += bf2f(u3.x); a3.y += bf2f(u3.y);
          }
          for (; j + 2 <= cnt; j += 2) {
            int s = __shfl(id, j + half);
            ushort2 u = gb2[s * 32 + kk];
            a0.x += bf2f(u.x); a0.y += bf2f(u.y);
          }
          if (j < cnt) {   // odd tail: only half 0 contributes
            int s = __shfl(id, j);
            if (half == 0) {
              ushort2 u = gb2[s * 32 + kk];
              a0.x += bf2f(u.x); a0.y += bf2f(u.y);
            }
          }
        }
        float tx = (a0.x + a1.x) + (a2.x + a3.x);
        float ty = (a0.y + a1.y) + (a2.y + a3.y);
        float ox = tx + __shfl_xor(tx, 32);
        float oy = ty + __shfl_xor(ty, 32);
        hl[mbase + r][lane] = feat[n * DFEAT + lane];
        if (half == 0)
          *(float2*)&hl[mbase + r][64 + 2 * kk] = make_float2(ox, oy);
      } else {
        float a0 = 0.f, a1 = 0.f, a2 = 0.f, a3 = 0.f;
        for (int base = 0; base < deg; base += 64) {
          int cnt = min(64, deg - base);
          int id = (base + lane < deg) ? edge_src[off + base + lane] : 0;
          int j = 0;
          for (; j + 8 <= cnt; j += 8) {
            int s0 = __shfl(id, j + 0), s1 = __shfl(id, j + 1);
            int s2 = __shfl(id, j + 2), s3 = __shfl(id, j + 3);
            int s4 = __shfl(id, j + 4), s5 = __shfl(id, j + 5);
            int s6 = __shfl(id, j + 6), s7 = __shfl(id, j + 7);
            a0 += feat[s0 * DFEAT + lane];
            a1 += feat[s1 * DFEAT + lane];
            a2 += feat[s2 * DFEAT + lane];
            a3 += feat[s3 * DFEAT + lane];
            a0 += feat[s4 * DFEAT + lane];
            a1 += feat[s5 * DFEAT + lane];
            a2 += feat[s6 * DFEAT + lane];
            a3 += feat[s7 * DFEAT + lane];
          }
          for (; j < cnt; ++j) {
            int s = __shfl(id, j);
            a0 += feat[s * DFEAT + lane];
          }
        }
        hl[mbase + r][lane]      = feat[n * DFEAT + lane];
        hl[mbase + r][64 + lane] = (a0 + a1) + (a2 + a3);
      }
    }
    __syncthreads();

    float c0 = 0.f, c1 = 0.f, c2 = 0.f, c3 = 0.f;
#pragma unroll 4
    for (int k4 = 0; k4 < 32; ++k4) {
      float4 w  = Wl4[k4 * 64 + (lane ^ (k4 & 7))];
      float4 h0 = *((const float4*)&hl[mbase + 0][k4 * 4]);
      float4 h1 = *((const float4*)&hl[mbase + 1][k4 * 4]);
      float4 h2 = *((const float4*)&hl[mbase + 2][k4 * 4]);
      float4 h3 = *((const float4*)&hl[mbase + 3][k4 * 4]);
      c0 += w.x * h0.x + w.y * h0.y + w.z * h0.z + w.w * h0.w;
      c1 += w.x * h1.x + w.y * h1.y + w.z * h1.z + w.w * h1.w;
      c2 += w.x * h2.x + w.y * h2.y + w.z * h2.z + w.w * h2.w;
      c3 += w.x * h3.x + w.y * h3.y + w.z * h3.z + w.w * h3.w;
    }

    int n = node0 + mbase;
    if (n + 0 < n_nodes) out[(n + 0) * DFEAT + lane] = c0 + bj;
    if (n + 1 < n_nodes) out[(n + 1) * DFEAT + lane] = c1 + bj;
    if (n + 2 < n_nodes) out[(n + 2) * DFEAT + lane] = c2 + bj;
    if (n + 3 < n_nodes) out[(n + 3) * DFEAT + lane] = c3 + bj;
    __syncthreads();
  }
}

// ===========================================================================
// Last-resort fallback: atomic scatter + separate GEMM.
// ===========================================================================
__global__ __launch_bounds__(256) void gcn_scatter_kernel(
    const float4* __restrict__ feat4, const int* __restrict__ src,
    const int* __restrict__ dst, float* __restrict__ agg, int n_edges) {
  long long gid = (long long)blockIdx.x * blockDim.x + threadIdx.x;
  int e = (int)(gid >> 4);
  int c = (int)(gid & 15);
  if (e >= n_edges) return;
  float4 v = feat4[src[e] * 16 + c];
  float* p = agg + dst[e] * DFEAT + c * 4;
  atomicAdd(p + 0, v.x);
  atomicAdd(p + 1, v.y);
  atomicAdd(p + 2, v.z);
  atomicAdd(p + 3, v.w);
}

__global__ __launch_bounds__(256) void gcn_gemm_kernel(
    const float* __restrict__ feat, const float* __restrict__ agg,
    const float* __restrict__ W, const float* __restrict__ bias,
    float* __restrict__ out, int n_nodes) {
  __shared__ float4 Wl4[2048];
  __shared__ __align__(16) float hl[NODES_PER_BLOCK][128];
  int tid = threadIdx.x;
  for (int i = tid; i < 2048; i += 256) {
    int j = i >> 5, k4 = i & 31;
    Wl4[k4 * 64 + (j ^ (k4 & 7))] = ((const float4*)W)[i];
  }
  int node0 = blockIdx.x * NODES_PER_BLOCK;
  int wave = tid >> 6, lane = tid & 63;
  int mbase = wave * 4;
#pragma unroll
  for (int r = 0; r < 4; ++r) {
    int n = node0 + mbase + r;
    if (n < n_nodes) {
      hl[mbase + r][lane]      = feat[n * DFEAT + lane];
      hl[mbase + r][64 + lane] = agg[n * DFEAT + lane];
    }
  }
  __syncthreads();
  float a0 = 0.f, a1 = 0.f, a2 = 0.f, a3 = 0.f;
#pragma unroll 4
  for (int k4 = 0; k4 < 32; ++k4) {
    float4 w  = Wl4[k4 * 64 + (lane ^ (k4 & 7))];
    float4 h0 = *((const float4*)&hl[mbase + 0][k4 * 4]);
    float4 h1 = *((const float4*)&hl[mbase + 1][k4 * 4]);
    float4 h2 = *((const float4*)&hl[mbase + 2][k4 * 4]);
    float4 h3 = *((const float4*)&hl[mbase + 3][k4 * 4]);
    a0 += w.x * h0.x + w.y * h0.y + w.z * h0.z + w.w * h0.w;
    a1 += w.x * h1.x + w.y * h1.y + w.z * h1.z + w.w * h1.w;
    a2 += w.x * h2.x + w.y * h2.y + w.z * h2.z + w.w * h2.w;
    a3 += w.x * h3.x + w.y * h3.y + w.z * h3.z + w.w * h3.w;
  }
  float bj = bias[lane];
  int n = node0 + mbase;
  if (n + 0 < n_nodes) out[(n + 0) * DFEAT + lane] = a0 + bj;
  if (n + 1 < n_nodes) out[(n + 1) * DFEAT + lane] = a1 + bj;
  if (n + 2 < n_nodes) out[(n + 2) * DFEAT + lane] = a2 + bj;
  if (n + 3 < n_nodes) out[(n + 3) * DFEAT + lane] = a3 + bj;
}

// ===========================================================================

extern "C" void kernel_launch(void* const* d_in, const int* in_sizes, int n_in,
                              void* d_out, int out_size, void* d_ws, size_t ws_size,
                              hipStream_t stream) {
  const float* feat = (const float*)d_in[0];
  const int*   src  = (const int*)d_in[1];
  const int*   dst  = (const int*)d_in[2];
  const float* W    = (const float*)d_in[3];
  const float* bias = (const float*)d_in[4];
  float* out = (float*)d_out;

  int n_nodes = in_sizes[0] / DFEAT;   // 100000
  int n_edges = in_sizes[1];           // 1600000
  int nbkt = (n_nodes + BKSZ - 1) >> SB;

  auto align_up = [](size_t x) { return (x + 255) & ~(size_t)255; };
  size_t gb_b   = align_up((size_t)n_nodes * DFEAT * 2);
  size_t esrc_b = align_up((size_t)n_edges * 4);
  size_t off_b  = align_up((size_t)(n_nodes + 1) * 4);
  size_t bcnt_b = align_up((size_t)MAXBKT * 4);
  size_t bbas_b = align_up((size_t)(MAXBKT + 1) * 4);
  size_t bcur_b = align_up((size_t)MAXBKT * 4);
  size_t small_b = esrc_b + off_b + bcnt_b + bbas_b + bcur_b;

  bool pairs_fit = (size_t)out_size * 4 >= (size_t)n_edges * 8;
  bool mid_ok  = pairs_fit && nbkt >= 1 && nbkt <= 1024 && ws_size >= small_b;
  bool full_ok = mid_ok && ws_size >= small_b + gb_b;

  if (mid_ok) {
    char* p = (char*)d_ws;
    int* edge_src = (int*)p;   p += esrc_b;
    int* offsets  = (int*)p;   p += off_b;
    int* bcnt     = (int*)p;   p += bcnt_b;
    int* bbase    = (int*)p;   p += bbas_b;
    int* bcur     = (int*)p;   p += bcur_b;
    unsigned short* gb = (unsigned short*)p;   // only used if full_ok
    int2* pairs = (int2*)d_out;                // dead before out is written

    hipMemsetAsync(bcnt, 0, (size_t)nbkt * 4, stream);
    if (full_ok) {
      int n4 = n_nodes * (DFEAT / 4);
      gcn_tobf16<<<(n4 + 255) / 256, 256, 0, stream>>>(
          (const float4*)feat, (ushort4*)gb, n4);
    }
    gcn_bcount<<<256, 256, 0, stream>>>(dst, bcnt, n_edges, nbkt);
    gcn_bscan<<<1, 1024, 0, stream>>>(bcnt, bbase, bcur, nbkt);
    int pblocks = (n_edges + PLACE_CHUNK - 1) / PLACE_CHUNK;
    gcn_bplace<<<pblocks, 256, 0, stream>>>(src, dst, bcur, pairs, n_edges, nbkt);
    gcn_bfill<<<nbkt, 512, 0, stream>>>(pairs, bbase, offsets, edge_src,
                                        n_nodes, n_edges, nbkt);

    int ntiles = (n_nodes + NODES_PER_BLOCK - 1) / NODES_PER_BLOCK;
    int gblocks = ntiles < 2048 ? ntiles : 2048;
    if (full_ok)
      gcn_gather_gemm<1><<<gblocks, 256, 0, stream>>>(
          feat, gb, edge_src, offsets, W, bias, out, n_nodes);
    else
      gcn_gather_gemm<0><<<gblocks, 256, 0, stream>>>(
          feat, (const unsigned short*)nullptr, edge_src, offsets, W, bias,
          out, n_nodes);
  } else {
    size_t agg_bytes = (size_t)n_nodes * DFEAT * sizeof(float);
    float* agg = (ws_size >= agg_bytes) ? (float*)d_ws : out;
    hipMemsetAsync(agg, 0, agg_bytes, stream);
    long long st = (long long)n_edges * 16;
    gcn_scatter_kernel<<<(int)((st + 255) / 256), 256, 0, stream>>>(
        (const float4*)feat, src, dst, agg, n_edges);
    int gblocks = (n_nodes + NODES_PER_BLOCK - 1) / NODES_PER_BLOCK;
    gcn_gemm_kernel<<<gblocks, 256, 0, stream>>>(feat, agg, W, bias, out, n_nodes);
  }
}

// Round 5
// 131.706 us; speedup vs baseline: 11.3468x; 1.3116x over previous
//
#include <hip/hip_runtime.h>

#define DFEAT 64
#define BKSZ 512            // nodes per bucket (CSR build)
#define SB 9                // log2(BKSZ)
#define MAXBKT 1024
#define PLACE_CHUNK 4096

typedef __attribute__((ext_vector_type(8))) short bf16x8;
typedef __attribute__((ext_vector_type(4))) float f32x4;

__device__ inline unsigned short f2bf(float f) {
  unsigned int x = __float_as_uint(f);
  return (unsigned short)((x + 0x7fffu + ((x >> 16) & 1u)) >> 16);
}
__device__ inline float bf2f(unsigned short u) {
  return __uint_as_float(((unsigned int)u) << 16);
}

// ===========================================================================
// fp32 -> bf16 conversion: feat table (n4 float4s) then W (nw4 float4s).
// ===========================================================================
__global__ __launch_bounds__(256) void gcn_tobf16(
    const float4* __restrict__ feat4, ushort4* __restrict__ gb4, int n4,
    const float4* __restrict__ w4, ushort4* __restrict__ wb4, int nw4) {
  int i = blockIdx.x * 256 + threadIdx.x;
  if (i < n4) {
    float4 f = feat4[i];
    ushort4 u;
    u.x = f2bf(f.x); u.y = f2bf(f.y); u.z = f2bf(f.z); u.w = f2bf(f.w);
    gb4[i] = u;
  } else if (i < n4 + nw4) {
    float4 f = w4[i - n4];
    ushort4 u;
    u.x = f2bf(f.x); u.y = f2bf(f.y); u.z = f2bf(f.z); u.w = f2bf(f.w);
    wb4[i - n4] = u;
  }
}

// ===========================================================================
// Bucketed counting sort (hist -> scan -> place -> per-bucket fill).
// ===========================================================================
__global__ __launch_bounds__(256) void gcn_bcount(
    const int* __restrict__ dst, int* __restrict__ bcnt,
    int n_edges, int nbkt) {
  __shared__ int h[MAXBKT];
  for (int i = threadIdx.x; i < nbkt; i += 256) h[i] = 0;
  __syncthreads();
  int n4 = n_edges >> 2;
  const int4* d4 = (const int4*)dst;
  for (int e = blockIdx.x * 256 + threadIdx.x; e < n4; e += gridDim.x * 256) {
    int4 v = d4[e];
    atomicAdd(&h[v.x >> SB], 1);
    atomicAdd(&h[v.y >> SB], 1);
    atomicAdd(&h[v.z >> SB], 1);
    atomicAdd(&h[v.w >> SB], 1);
  }
  if (blockIdx.x == 0)
    for (int e = (n4 << 2) + threadIdx.x; e < n_edges; e += 256)
      atomicAdd(&h[dst[e] >> SB], 1);
  __syncthreads();
  for (int i = threadIdx.x; i < nbkt; i += 256)
    if (h[i]) atomicAdd(&bcnt[i], h[i]);
}

__global__ __launch_bounds__(1024) void gcn_bscan(
    const int* __restrict__ bcnt, int* __restrict__ bbase,
    int* __restrict__ bcur, int nbkt) {
  __shared__ int buf[2][1024];
  int t = threadIdx.x;
  int v = (t < nbkt) ? bcnt[t] : 0;
  buf[0][t] = v;
  __syncthreads();
  int pin = 0;
  for (int s = 1; s < 1024; s <<= 1) {
    int po = pin ^ 1;
    int val = buf[pin][t];
    if (t >= s) val += buf[pin][t - s];
    buf[po][t] = val;
    __syncthreads();
    pin = po;
  }
  if (t < nbkt) {
    int excl = (t == 0) ? 0 : buf[pin][t - 1];
    bbase[t] = excl;
    bcur[t] = excl;
    if (t == nbkt - 1) bbase[nbkt] = buf[pin][t];
  }
}

__global__ __launch_bounds__(256) void gcn_bplace(
    const int* __restrict__ src, const int* __restrict__ dst,
    int* __restrict__ bcur, int2* __restrict__ pairs,
    int n_edges, int nbkt) {
  __shared__ int cnt[MAXBKT];
  __shared__ int base[MAXBKT];
  int t = threadIdx.x;
  int e0 = blockIdx.x * PLACE_CHUNK;
  int e1 = min(e0 + PLACE_CHUNK, n_edges);
  for (int i = t; i < nbkt; i += 256) cnt[i] = 0;
  __syncthreads();
  for (int e = e0 + t; e < e1; e += 256)
    atomicAdd(&cnt[dst[e] >> SB], 1);
  __syncthreads();
  for (int i = t; i < nbkt; i += 256) {
    int c = cnt[i];
    base[i] = c ? atomicAdd(&bcur[i], c) : 0;
    cnt[i] = 0;   // reuse as local cursor
  }
  __syncthreads();
  for (int e = e0 + t; e < e1; e += 256) {
    int d = dst[e];
    int b = d >> SB;
    int pos = base[b] + atomicAdd(&cnt[b], 1);
    pairs[pos] = make_int2(src[e], d);
  }
}

__global__ __launch_bounds__(512) void gcn_bfill(
    const int2* __restrict__ pairs, const int* __restrict__ bbase,
    int* __restrict__ offsets, int* __restrict__ edge_src,
    int n_nodes, int n_edges, int nbkt) {
  __shared__ int deg[BKSZ];
  __shared__ int buf[2][BKSZ];
  __shared__ int cur[BKSZ];
  int b = blockIdx.x;
  int t = threadIdx.x;
  int n0 = b << SB;
  int e0 = bbase[b], e1 = bbase[b + 1];
  deg[t] = 0;
  __syncthreads();
  for (int e = e0 + t; e < e1; e += 512)
    atomicAdd(&deg[pairs[e].y - n0], 1);
  __syncthreads();
  buf[0][t] = deg[t];
  __syncthreads();
  int pin = 0;
  for (int s = 1; s < BKSZ; s <<= 1) {
    int po = pin ^ 1;
    int v = buf[pin][t];
    if (t >= s) v += buf[pin][t - s];
    buf[po][t] = v;
    __syncthreads();
    pin = po;
  }
  int excl = (t == 0) ? 0 : buf[pin][t - 1];
  cur[t] = excl;
  int n = n0 + t;
  if (n < n_nodes) offsets[n] = e0 + excl;
  if (b == nbkt - 1 && t == 0) offsets[n_nodes] = n_edges;
  __syncthreads();
  for (int e = e0 + t; e < e1; e += 512) {
    int2 p = pairs[e];
    int pos = atomicAdd(&cur[p.y - n0], 1);
    edge_src[e0 + pos] = p.x;
  }
}

// ===========================================================================
// Fused gather + concat + MFMA Linear.
// Block = 4 waves; each wave owns 16 nodes, fully independent (no barriers).
//
// Gather (bf16): 2 edges per wave (lane = 32*half + kk, ushort2/lane);
// 16-edge unroll -> 8 independent loads in flight.
//
// h staged bf16 in wave-private LDS [16 rows][256B], XOR-swizzled
// (byte ^= (row&7)<<4) so A-frag ds_read_b128 (lane&15 = row, stride 256B)
// avoids the 16-way bank conflict (G4 pattern).
//
// GEMM: out[16][64] = h[16][128] @ W^T via 16x16x32 bf16 MFMA.
// W lives in REGISTERS as B-frags (wf[kt][jt], 64 VGPR), loaded after the
// gather.  A/B frags use identical (lane>>4, elem)->k indexing, so the k
// permutation cancels; C/D: col=lane&15, row=(lane>>4)*4+reg (m89-verified).
// ===========================================================================
__global__ __launch_bounds__(256, 4) void gcn_gather_mfma(
    const unsigned short* __restrict__ gb,   // [N][64] bf16 feat
    const unsigned short* __restrict__ wb,   // [64][128] bf16 W
    const int* __restrict__ edge_src,
    const int* __restrict__ offsets,
    const float* __restrict__ bias,          // [64]
    float* __restrict__ out,                 // [N][64]
    int n_nodes) {
  __shared__ unsigned short hl[4][16 * 128];   // 16 KB total
  int tid = threadIdx.x;
  int wave = tid >> 6, lane = tid & 63;
  int half = lane >> 5, kk = lane & 31;
  int lrow = lane & 15, lkg = lane >> 4;
  const ushort2* gb2 = (const ushort2*)gb;
  unsigned short* myhl = hl[wave];

  int node0 = blockIdx.x * 64 + wave * 16;

  // ---- gather 16 nodes (wave-private) ----
  for (int r = 0; r < 16; ++r) {
    int n = node0 + r;
    if (n >= n_nodes) break;
    int off = offsets[n];
    int deg = offsets[n + 1] - off;

    float2 a0 = {0.f, 0.f}, a1 = {0.f, 0.f};
    float2 a2 = {0.f, 0.f}, a3 = {0.f, 0.f};
    for (int base = 0; base < deg; base += 64) {
      int cnt = min(64, deg - base);
      int id = (base + lane < deg) ? edge_src[off + base + lane] : 0;
      int j = 0;
      for (; j + 16 <= cnt; j += 16) {
        int s0 = __shfl(id, j + 0 + half);
        int s1 = __shfl(id, j + 2 + half);
        int s2 = __shfl(id, j + 4 + half);
        int s3 = __shfl(id, j + 6 + half);
        int s4 = __shfl(id, j + 8 + half);
        int s5 = __shfl(id, j + 10 + half);
        int s6 = __shfl(id, j + 12 + half);
        int s7 = __shfl(id, j + 14 + half);
        ushort2 u0 = gb2[s0 * 32 + kk];
        ushort2 u1 = gb2[s1 * 32 + kk];
        ushort2 u2 = gb2[s2 * 32 + kk];
        ushort2 u3 = gb2[s3 * 32 + kk];
        ushort2 u4 = gb2[s4 * 32 + kk];
        ushort2 u5 = gb2[s5 * 32 + kk];
        ushort2 u6 = gb2[s6 * 32 + kk];
        ushort2 u7 = gb2[s7 * 32 + kk];
        a0.x += bf2f(u0.x); a0.y += bf2f(u0.y);
        a1.x += bf2f(u1.x); a1.y += bf2f(u1.y);
        a2.x += bf2f(u2.x); a2.y += bf2f(u2.y);
        a3.x += bf2f(u3.x); a3.y += bf2f(u3.y);
        a0.x += bf2f(u4.x); a0.y += bf2f(u4.y);
        a1.x += bf2f(u5.x); a1.y += bf2f(u5.y);
        a2.x += bf2f(u6.x); a2.y += bf2f(u6.y);
        a3.x += bf2f(u7.x); a3.y += bf2f(u7.y);
      }
      for (; j + 2 <= cnt; j += 2) {
        int s = __shfl(id, j + half);
        ushort2 u = gb2[s * 32 + kk];
        a0.x += bf2f(u.x); a0.y += bf2f(u.y);
      }
      if (j < cnt) {   // odd tail: only half 0 contributes
        int s = __shfl(id, j);
        if (half == 0) {
          ushort2 u = gb2[s * 32 + kk];
          a0.x += bf2f(u.x); a0.y += bf2f(u.y);
        }
      }
    }
    float tx = (a0.x + a1.x) + (a2.x + a3.x);
    float ty = (a0.y + a1.y) + (a2.y + a3.y);
    float ox = tx + __shfl_xor(tx, 32);
    float oy = ty + __shfl_xor(ty, 32);

    unsigned swz = (unsigned)((r & 7) << 4);
    char* rowp = (char*)(myhl + r * 128);
    if (half == 0) {          // feat half: bytes [0,128)
      ushort2 f = gb2[n * 32 + kk];
      *(ushort2*)(rowp + ((4u * kk) ^ swz)) = f;
    } else {                  // agg half: bytes [128,256)
      ushort2 pk;
      pk.x = f2bf(ox); pk.y = f2bf(oy);
      *(ushort2*)(rowp + ((128u + 4u * kk) ^ swz)) = pk;
    }
  }

  // ---- W B-frags into registers (after gather to keep its VGPRs low) ----
  bf16x8 wf[4][4];
#pragma unroll
  for (int kt = 0; kt < 4; ++kt)
#pragma unroll
    for (int jt = 0; jt < 4; ++jt)
      wf[kt][jt] =
          *(const bf16x8*)(wb + (jt * 16 + lrow) * 128 + kt * 32 + lkg * 8);

  // ---- MFMA: 4 A-frag reads + 16 mfma ----
  f32x4 acc[4];
#pragma unroll
  for (int jt = 0; jt < 4; ++jt) acc[jt] = (f32x4){0.f, 0.f, 0.f, 0.f};

  unsigned aswz = (unsigned)((lrow & 7) << 4);
  const char* arow = (const char*)(myhl + lrow * 128);
#pragma unroll
  for (int kt = 0; kt < 4; ++kt) {
    bf16x8 af = *(const bf16x8*)(arow + ((unsigned)(kt * 64 + lkg * 16) ^ aswz));
#pragma unroll
    for (int jt = 0; jt < 4; ++jt)
      acc[jt] = __builtin_amdgcn_mfma_f32_16x16x32_bf16(af, wf[kt][jt],
                                                        acc[jt], 0, 0, 0);
  }

#pragma unroll
  for (int jt = 0; jt < 4; ++jt) {
    float bj = bias[jt * 16 + lrow];
#pragma unroll
    for (int r = 0; r < 4; ++r) {
      int n = node0 + lkg * 4 + r;
      if (n < n_nodes) out[n * DFEAT + jt * 16 + lrow] = acc[jt][r] + bj;
    }
  }
}

// ===========================================================================
// fp32 fallback fused kernel (only if ws can't hold the bf16 tables).
// ===========================================================================
__global__ __launch_bounds__(256, 4) void gcn_gather_gemm_f32(
    const float* __restrict__ feat, const int* __restrict__ edge_src,
    const int* __restrict__ offsets, const float* __restrict__ W,
    const float* __restrict__ bias, float* __restrict__ out, int n_nodes) {
  __shared__ float4 Wl4[2048];
  __shared__ __align__(16) float hlf[16][128];
  int tid = threadIdx.x;
  int wave = tid >> 6, lane = tid & 63;
  int mbase = wave * 4;
  for (int i = tid; i < 2048; i += 256) {
    int j = i >> 5, k4 = i & 31;
    Wl4[k4 * 64 + (j ^ (k4 & 7))] = ((const float4*)W)[i];
  }
  float bj = bias[lane];
  for (int node0 = blockIdx.x * 16; node0 < n_nodes; node0 += gridDim.x * 16) {
    for (int r = 0; r < 4; ++r) {
      int n = node0 + mbase + r;
      if (n >= n_nodes) break;
      int off = offsets[n];
      int deg = offsets[n + 1] - off;
      float a0 = 0.f, a1 = 0.f, a2 = 0.f, a3 = 0.f;
      for (int base = 0; base < deg; base += 64) {
        int cnt = min(64, deg - base);
        int id = (base + lane < deg) ? edge_src[off + base + lane] : 0;
        int j = 0;
        for (; j + 8 <= cnt; j += 8) {
          int s0 = __shfl(id, j + 0), s1 = __shfl(id, j + 1);
          int s2 = __shfl(id, j + 2), s3 = __shfl(id, j + 3);
          int s4 = __shfl(id, j + 4), s5 = __shfl(id, j + 5);
          int s6 = __shfl(id, j + 6), s7 = __shfl(id, j + 7);
          a0 += feat[s0 * DFEAT + lane];
          a1 += feat[s1 * DFEAT + lane];
          a2 += feat[s2 * DFEAT + lane];
          a3 += feat[s3 * DFEAT + lane];
          a0 += feat[s4 * DFEAT + lane];
          a1 += feat[s5 * DFEAT + lane];
          a2 += feat[s6 * DFEAT + lane];
          a3 += feat[s7 * DFEAT + lane];
        }
        for (; j < cnt; ++j) {
          int s = __shfl(id, j);
          a0 += feat[s * DFEAT + lane];
        }
      }
      hlf[mbase + r][lane]      = feat[n * DFEAT + lane];
      hlf[mbase + r][64 + lane] = (a0 + a1) + (a2 + a3);
    }
    __syncthreads();
    float c0 = 0.f, c1 = 0.f, c2 = 0.f, c3 = 0.f;
#pragma unroll 4
    for (int k4 = 0; k4 < 32; ++k4) {
      float4 w  = Wl4[k4 * 64 + (lane ^ (k4 & 7))];
      float4 h0 = *((const float4*)&hlf[mbase + 0][k4 * 4]);
      float4 h1 = *((const float4*)&hlf[mbase + 1][k4 * 4]);
      float4 h2 = *((const float4*)&hlf[mbase + 2][k4 * 4]);
      float4 h3 = *((const float4*)&hlf[mbase + 3][k4 * 4]);
      c0 += w.x * h0.x + w.y * h0.y + w.z * h0.z + w.w * h0.w;
      c1 += w.x * h1.x + w.y * h1.y + w.z * h1.z + w.w * h1.w;
      c2 += w.x * h2.x + w.y * h2.y + w.z * h2.z + w.w * h2.w;
      c3 += w.x * h3.x + w.y * h3.y + w.z * h3.z + w.w * h3.w;
    }
    int n = node0 + mbase;
    if (n + 0 < n_nodes) out[(n + 0) * DFEAT + lane] = c0 + bj;
    if (n + 1 < n_nodes) out[(n + 1) * DFEAT + lane] = c1 + bj;
    if (n + 2 < n_nodes) out[(n + 2) * DFEAT + lane] = c2 + bj;
    if (n + 3 < n_nodes) out[(n + 3) * DFEAT + lane] = c3 + bj;
    __syncthreads();
  }
}

// ===========================================================================
// Last-resort fallback: atomic scatter + separate GEMM.
// ===========================================================================
__global__ __launch_bounds__(256) void gcn_scatter_kernel(
    const float4* __restrict__ feat4, const int* __restrict__ src,
    const int* __restrict__ dst, float* __restrict__ agg, int n_edges) {
  long long gid = (long long)blockIdx.x * blockDim.x + threadIdx.x;
  int e = (int)(gid >> 4);
  int c = (int)(gid & 15);
  if (e >= n_edges) return;
  float4 v = feat4[src[e] * 16 + c];
  float* p = agg + dst[e] * DFEAT + c * 4;
  atomicAdd(p + 0, v.x);
  atomicAdd(p + 1, v.y);
  atomicAdd(p + 2, v.z);
  atomicAdd(p + 3, v.w);
}

__global__ __launch_bounds__(256) void gcn_gemm_kernel(
    const float* __restrict__ feat, const float* __restrict__ agg,
    const float* __restrict__ W, const float* __restrict__ bias,
    float* __restrict__ out, int n_nodes) {
  __shared__ float4 Wl4[2048];
  __shared__ __align__(16) float hlf[16][128];
  int tid = threadIdx.x;
  for (int i = tid; i < 2048; i += 256) {
    int j = i >> 5, k4 = i & 31;
    Wl4[k4 * 64 + (j ^ (k4 & 7))] = ((const float4*)W)[i];
  }
  int node0 = blockIdx.x * 16;
  int wave = tid >> 6, lane = tid & 63;
  int mbase = wave * 4;
#pragma unroll
  for (int r = 0; r < 4; ++r) {
    int n = node0 + mbase + r;
    if (n < n_nodes) {
      hlf[mbase + r][lane]      = feat[n * DFEAT + lane];
      hlf[mbase + r][64 + lane] = agg[n * DFEAT + lane];
    }
  }
  __syncthreads();
  float a0 = 0.f, a1 = 0.f, a2 = 0.f, a3 = 0.f;
#pragma unroll 4
  for (int k4 = 0; k4 < 32; ++k4) {
    float4 w  = Wl4[k4 * 64 + (lane ^ (k4 & 7))];
    float4 h0 = *((const float4*)&hlf[mbase + 0][k4 * 4]);
    float4 h1 = *((const float4*)&hlf[mbase + 1][k4 * 4]);
    float4 h2 = *((const float4*)&hlf[mbase + 2][k4 * 4]);
    float4 h3 = *((const float4*)&hlf[mbase + 3][k4 * 4]);
    a0 += w.x * h0.x + w.y * h0.y + w.z * h0.z + w.w * h0.w;
    a1 += w.x * h1.x + w.y * h1.y + w.z * h1.z + w.w * h1.w;
    a2 += w.x * h2.x + w.y * h2.y + w.z * h2.z + w.w * h2.w;
    a3 += w.x * h3.x + w.y * h3.y + w.z * h3.z + w.w * h3.w;
  }
  float bj = bias[lane];
  int n = node0 + mbase;
  if (n + 0 < n_nodes) out[(n + 0) * DFEAT + lane] = a0 + bj;
  if (n + 1 < n_nodes) out[(n + 1) * DFEAT + lane] = a1 + bj;
  if (n + 2 < n_nodes) out[(n + 2) * DFEAT + lane] = a2 + bj;
  if (n + 3 < n_nodes) out[(n + 3) * DFEAT + lane] = a3 + bj;
}

// ===========================================================================

extern "C" void kernel_launch(void* const* d_in, const int* in_sizes, int n_in,
                              void* d_out, int out_size, void* d_ws, size_t ws_size,
                              hipStream_t stream) {
  const float* feat = (const float*)d_in[0];
  const int*   src  = (const int*)d_in[1];
  const int*   dst  = (const int*)d_in[2];
  const float* W    = (const float*)d_in[3];
  const float* bias = (const float*)d_in[4];
  float* out = (float*)d_out;

  int n_nodes = in_sizes[0] / DFEAT;   // 100000
  int n_edges = in_sizes[1];           // 1600000
  int nbkt = (n_nodes + BKSZ - 1) >> SB;

  auto align_up = [](size_t x) { return (x + 255) & ~(size_t)255; };
  size_t gb_b   = align_up((size_t)n_nodes * DFEAT * 2);
  size_t wb_b   = align_up((size_t)DFEAT * 128 * 2);
  size_t esrc_b = align_up((size_t)n_edges * 4);
  size_t off_b  = align_up((size_t)(n_nodes + 1) * 4);
  size_t bcnt_b = align_up((size_t)MAXBKT * 4);
  size_t bbas_b = align_up((size_t)(MAXBKT + 1) * 4);
  size_t bcur_b = align_up((size_t)MAXBKT * 4);
  size_t small_b = esrc_b + off_b + bcnt_b + bbas_b + bcur_b + wb_b;

  bool pairs_fit = (size_t)out_size * 4 >= (size_t)n_edges * 8;
  bool mid_ok  = pairs_fit && nbkt >= 1 && nbkt <= 1024 && ws_size >= small_b;
  bool full_ok = mid_ok && ws_size >= small_b + gb_b;

  if (mid_ok) {
    char* p = (char*)d_ws;
    int* edge_src = (int*)p;   p += esrc_b;
    int* offsets  = (int*)p;   p += off_b;
    int* bcnt     = (int*)p;   p += bcnt_b;
    int* bbase    = (int*)p;   p += bbas_b;
    int* bcur     = (int*)p;   p += bcur_b;
    unsigned short* wb = (unsigned short*)p;   p += wb_b;
    unsigned short* gb = (unsigned short*)p;   // only used if full_ok
    int2* pairs = (int2*)d_out;                // dead before out is written

    hipMemsetAsync(bcnt, 0, (size_t)nbkt * 4, stream);
    if (full_ok) {
      int n4 = n_nodes * (DFEAT / 4);
      int nw4 = DFEAT * 128 / 4;
      gcn_tobf16<<<(n4 + nw4 + 255) / 256, 256, 0, stream>>>(
          (const float4*)feat, (ushort4*)gb, n4,
          (const float4*)W, (ushort4*)wb, nw4);
    }
    gcn_bcount<<<256, 256, 0, stream>>>(dst, bcnt, n_edges, nbkt);
    gcn_bscan<<<1, 1024, 0, stream>>>(bcnt, bbase, bcur, nbkt);
    int pblocks = (n_edges + PLACE_CHUNK - 1) / PLACE_CHUNK;
    gcn_bplace<<<pblocks, 256, 0, stream>>>(src, dst, bcur, pairs, n_edges, nbkt);
    gcn_bfill<<<nbkt, 512, 0, stream>>>(pairs, bbase, offsets, edge_src,
                                        n_nodes, n_edges, nbkt);

    if (full_ok) {
      int gblocks = (n_nodes + 63) / 64;
      gcn_gather_mfma<<<gblocks, 256, 0, stream>>>(
          gb, wb, edge_src, offsets, bias, out, n_nodes);
    } else {
      int ntiles = (n_nodes + 15) / 16;
      int gblocks = ntiles < 2048 ? ntiles : 2048;
      gcn_gather_gemm_f32<<<gblocks, 256, 0, stream>>>(
          feat, edge_src, offsets, W, bias, out, n_nodes);
    }
  } else {
    size_t agg_bytes = (size_t)n_nodes * DFEAT * sizeof(float);
    float* agg = (ws_size >= agg_bytes) ? (float*)d_ws : out;
    hipMemsetAsync(agg, 0, agg_bytes, stream);
    long long st = (long long)n_edges * 16;
    gcn_scatter_kernel<<<(int)((st + 255) / 256), 256, 0, stream>>>(
        (const float4*)feat, src, dst, agg, n_edges);
    int gblocks = (n_nodes + 15) / 16;
    gcn_gemm_kernel<<<gblocks, 256, 0, stream>>>(feat, agg, W, bias, out, n_nodes);
  }
}

// Round 6
// 130.344 us; speedup vs baseline: 11.4653x; 1.0104x over previous
//
#include <hip/hip_runtime.h>

#define DFEAT 64
#define BKSZ 512            // nodes per bucket (CSR build)
#define SB 9                // log2(BKSZ)
#define NBKT_PAD 256        // max buckets handled by the local-scan path
#define PLACE_CHUNK 4096

typedef __attribute__((ext_vector_type(8))) short bf16x8;
typedef __attribute__((ext_vector_type(4))) float f32x4;

__device__ inline unsigned short f2bf(float f) {
  unsigned int x = __float_as_uint(f);
  return (unsigned short)((x + 0x7fffu + ((x >> 16) & 1u)) >> 16);
}

// ===========================================================================
// K1: fp32->bf16 conversion (feat + sentinel zero row + W) AND bucket hist.
// Independent jobs fused to save a dispatch.
// ===========================================================================
__global__ __launch_bounds__(256) void gcn_prep(
    const float4* __restrict__ feat4, ushort4* __restrict__ gb4, int n4,
    const float4* __restrict__ w4, ushort4* __restrict__ wb4, int nw4,
    const int* __restrict__ dst, int* __restrict__ bcnt,
    int n_edges, int nbkt) {
  // --- conversion: [0,n4) feat, [n4,n4+16) sentinel zeros, then W ---
  int total = n4 + 16 + nw4;
  for (int i = blockIdx.x * 256 + threadIdx.x; i < total; i += gridDim.x * 256) {
    if (i < n4) {
      float4 f = feat4[i];
      ushort4 u;
      u.x = f2bf(f.x); u.y = f2bf(f.y); u.z = f2bf(f.z); u.w = f2bf(f.w);
      gb4[i] = u;
    } else if (i < n4 + 16) {
      gb4[i] = (ushort4){0, 0, 0, 0};          // sentinel row (node n_nodes)
    } else {
      float4 f = w4[i - n4 - 16];
      ushort4 u;
      u.x = f2bf(f.x); u.y = f2bf(f.y); u.z = f2bf(f.z); u.w = f2bf(f.w);
      wb4[i - n4 - 16] = u;
    }
  }
  // --- bucket histogram (LDS, one global flush per block) ---
  __shared__ int h[NBKT_PAD];
  for (int i = threadIdx.x; i < nbkt; i += 256) h[i] = 0;
  __syncthreads();
  int ne4 = n_edges >> 2;
  const int4* d4 = (const int4*)dst;
  for (int e = blockIdx.x * 256 + threadIdx.x; e < ne4; e += gridDim.x * 256) {
    int4 v = d4[e];
    atomicAdd(&h[v.x >> SB], 1);
    atomicAdd(&h[v.y >> SB], 1);
    atomicAdd(&h[v.z >> SB], 1);
    atomicAdd(&h[v.w >> SB], 1);
  }
  if (blockIdx.x == 0)
    for (int e = (ne4 << 2) + threadIdx.x; e < n_edges; e += 256)
      atomicAdd(&h[dst[e] >> SB], 1);
  __syncthreads();
  for (int i = threadIdx.x; i < nbkt; i += 256)
    if (h[i]) atomicAdd(&bcnt[i], h[i]);
}

// ===========================================================================
// K2: place (src,dst) pairs grouped by bucket.  Computes the bucket base
// offsets via a LOCAL scan of bcnt (no separate scan kernel); bcur holds
// RELATIVE cursors (pre-zeroed).
// ===========================================================================
__global__ __launch_bounds__(256) void gcn_place(
    const int* __restrict__ src, const int* __restrict__ dst,
    const int* __restrict__ bcnt, int* __restrict__ bcur,
    int2* __restrict__ pairs, int n_edges, int nbkt) {
  __shared__ int sc[2][NBKT_PAD];
  __shared__ int cnt[NBKT_PAD];
  __shared__ int base[NBKT_PAD];
  int t = threadIdx.x;
  sc[0][t] = (t < nbkt) ? bcnt[t] : 0;
  __syncthreads();
  int pin = 0;
  for (int s = 1; s < NBKT_PAD; s <<= 1) {
    int po = pin ^ 1;
    int v = sc[pin][t];
    if (t >= s) v += sc[pin][t - s];
    sc[po][t] = v;
    __syncthreads();
    pin = po;
  }
  int bb = (t == 0) ? 0 : sc[pin][t - 1];   // exclusive bucket base

  cnt[t] = 0;
  __syncthreads();
  int e0 = blockIdx.x * PLACE_CHUNK;
  int e1 = min(e0 + PLACE_CHUNK, n_edges);
  for (int e = e0 + t; e < e1; e += 256) atomicAdd(&cnt[dst[e] >> SB], 1);
  __syncthreads();
  int c = cnt[t];
  base[t] = bb + (c ? atomicAdd(&bcur[t], c) : 0);
  cnt[t] = 0;   // reuse as local cursor
  __syncthreads();
  for (int e = e0 + t; e < e1; e += 256) {
    int d = dst[e];
    int b = d >> SB;
    int pos = base[b] + atomicAdd(&cnt[b], 1);
    pairs[pos] = make_int2(src[e], d);
  }
}

// ===========================================================================
// K3: per-bucket fill: local bucket-scan for [e0,e1), node-degree hist,
// node scan -> offsets, cursor placement of edge_src (33KB window).
// ===========================================================================
__global__ __launch_bounds__(512) void gcn_fillk(
    const int2* __restrict__ pairs, const int* __restrict__ bcnt,
    int* __restrict__ offsets, int* __restrict__ edge_src,
    int n_nodes, int n_edges, int nbkt) {
  __shared__ int sc[2][NBKT_PAD];
  __shared__ int deg[BKSZ];
  __shared__ int buf[2][BKSZ];
  __shared__ int cur[BKSZ];
  int b = blockIdx.x, t = threadIdx.x;
  if (t < NBKT_PAD) sc[0][t] = (t < nbkt) ? bcnt[t] : 0;
  __syncthreads();
  int pin = 0;
  for (int s = 1; s < NBKT_PAD; s <<= 1) {
    int po = pin ^ 1;
    if (t < NBKT_PAD) {
      int v = sc[pin][t];
      if (t >= s) v += sc[pin][t - s];
      sc[po][t] = v;
    }
    __syncthreads();
    pin = po;
  }
  int e0 = (b == 0) ? 0 : sc[pin][b - 1];
  int e1 = sc[pin][b];
  int n0 = b << SB;

  deg[t] = 0;
  __syncthreads();
  for (int e = e0 + t; e < e1; e += 512) atomicAdd(&deg[pairs[e].y - n0], 1);
  __syncthreads();
  buf[0][t] = deg[t];
  __syncthreads();
  pin = 0;
  for (int s = 1; s < BKSZ; s <<= 1) {
    int po = pin ^ 1;
    int v = buf[pin][t];
    if (t >= s) v += buf[pin][t - s];
    buf[po][t] = v;
    __syncthreads();
    pin = po;
  }
  int excl = (t == 0) ? 0 : buf[pin][t - 1];
  cur[t] = excl;
  int n = n0 + t;
  if (n < n_nodes) offsets[n] = e0 + excl;
  if (b == nbkt - 1 && t == 0) offsets[n_nodes] = n_edges;
  __syncthreads();
  for (int e = e0 + t; e < e1; e += 512) {
    int2 p = pairs[e];
    int pos = atomicAdd(&cur[p.y - n0], 1);
    edge_src[e0 + pos] = p.x;
  }
}

// ===========================================================================
// K4: fused gather + concat + MFMA Linear.
// Block = 4 waves; each wave owns 16 nodes, fully independent (no barriers).
//
// Gather: 4 edges per load instruction (lane = 16-lane group q per edge,
// ushort4 = 8B/lane, 512B/wave-inst).  Sentinel node id = n_nodes (zero row)
// pads every batch -> NO serial tail loops; 4 independent loads in flight
// per 16-edge step.  bf16->f32 via shl/and (1 VALU/byte).  Cross-group
// reduce: 8 shfl_xor per node.
//
// h staged bf16 in wave-private LDS [16 rows][256B], XOR-swizzled
// (byte ^= (r&7)<<4) so the A-frag ds_read_b128 avoids bank conflicts.
// W in REGISTERS as B-frags; A/B frags share the (lane>>4, elem)->k map so
// the k permutation cancels; C/D: col=lane&15, row=(lane>>4)*4+reg.
// ===========================================================================
__global__ __launch_bounds__(256, 4) void gcn_gather_mfma(
    const ushort4* __restrict__ gb4,         // [N+1][16] bf16, row N = zeros
    const unsigned short* __restrict__ wb,   // [64][128] bf16 W
    const int* __restrict__ edge_src,
    const int* __restrict__ offsets,
    const float* __restrict__ bias,          // [64]
    float* __restrict__ out,                 // [N][64]
    int n_nodes) {
  __shared__ unsigned short hl[4][16 * 128];   // 16 KB total
  int tid = threadIdx.x;
  int wave = tid >> 6, lane = tid & 63;
  int q = lane >> 4, kk = lane & 15;
  int lrow = lane & 15, lkg = lane >> 4;
  unsigned short* myhl = hl[wave];
  int node0 = blockIdx.x * 64 + wave * 16;
  const int SENT = n_nodes;

  // ---- gather 16 nodes (wave-private) ----
  for (int r = 0; r < 16; ++r) {
    int n = node0 + r;
    if (n >= n_nodes) break;
    int off = offsets[n];
    int deg = offsets[n + 1] - off;

    float4 a0 = {0.f, 0.f, 0.f, 0.f}, a1 = a0, a2 = a0, a3 = a0;
    for (int base = 0; base < deg; base += 64) {
      int lim = min(64, deg - base);
      int id = (base + lane < deg) ? edge_src[off + base + lane] : SENT;
      for (int j = 0; j < lim; j += 16) {
        int s0 = __shfl(id, j + q);
        int s1 = __shfl(id, j + 4 + q);
        int s2 = __shfl(id, j + 8 + q);
        int s3 = __shfl(id, j + 12 + q);
        uint2 w0 = *(const uint2*)&gb4[s0 * 16 + kk];
        uint2 w1 = *(const uint2*)&gb4[s1 * 16 + kk];
        uint2 w2 = *(const uint2*)&gb4[s2 * 16 + kk];
        uint2 w3 = *(const uint2*)&gb4[s3 * 16 + kk];
        a0.x += __uint_as_float(w0.x << 16);
        a0.y += __uint_as_float(w0.x & 0xffff0000u);
        a0.z += __uint_as_float(w0.y << 16);
        a0.w += __uint_as_float(w0.y & 0xffff0000u);
        a1.x += __uint_as_float(w1.x << 16);
        a1.y += __uint_as_float(w1.x & 0xffff0000u);
        a1.z += __uint_as_float(w1.y << 16);
        a1.w += __uint_as_float(w1.y & 0xffff0000u);
        a2.x += __uint_as_float(w2.x << 16);
        a2.y += __uint_as_float(w2.x & 0xffff0000u);
        a2.z += __uint_as_float(w2.y << 16);
        a2.w += __uint_as_float(w2.y & 0xffff0000u);
        a3.x += __uint_as_float(w3.x << 16);
        a3.y += __uint_as_float(w3.x & 0xffff0000u);
        a3.z += __uint_as_float(w3.y << 16);
        a3.w += __uint_as_float(w3.y & 0xffff0000u);
      }
    }
    float4 acc;
    acc.x = (a0.x + a1.x) + (a2.x + a3.x);
    acc.y = (a0.y + a1.y) + (a2.y + a3.y);
    acc.z = (a0.z + a1.z) + (a2.z + a3.z);
    acc.w = (a0.w + a1.w) + (a2.w + a3.w);
    acc.x += __shfl_xor(acc.x, 16); acc.x += __shfl_xor(acc.x, 32);
    acc.y += __shfl_xor(acc.y, 16); acc.y += __shfl_xor(acc.y, 32);
    acc.z += __shfl_xor(acc.z, 16); acc.z += __shfl_xor(acc.z, 32);
    acc.w += __shfl_xor(acc.w, 16); acc.w += __shfl_xor(acc.w, 32);

    unsigned swz = (unsigned)((r & 7) << 4);
    char* rowp = (char*)(myhl + r * 128);
    if (q == 0) {                 // agg half: bytes [128,256)
      ushort4 pk;
      pk.x = f2bf(acc.x); pk.y = f2bf(acc.y);
      pk.z = f2bf(acc.z); pk.w = f2bf(acc.w);
      *(ushort4*)(rowp + ((128u + 8u * (unsigned)kk) ^ swz)) = pk;
    } else if (q == 1) {          // feat half: bytes [0,128)
      ushort4 f = gb4[n * 16 + kk];
      *(ushort4*)(rowp + ((8u * (unsigned)kk) ^ swz)) = f;
    }
  }

  // ---- W B-frags into registers ----
  bf16x8 wf[4][4];
#pragma unroll
  for (int kt = 0; kt < 4; ++kt)
#pragma unroll
    for (int jt = 0; jt < 4; ++jt)
      wf[kt][jt] =
          *(const bf16x8*)(wb + (jt * 16 + lrow) * 128 + kt * 32 + lkg * 8);

  // ---- MFMA: 4 A-frag reads + 16 mfma ----
  f32x4 acc[4];
#pragma unroll
  for (int jt = 0; jt < 4; ++jt) acc[jt] = (f32x4){0.f, 0.f, 0.f, 0.f};

  unsigned aswz = (unsigned)((lrow & 7) << 4);
  const char* arow = (const char*)(myhl + lrow * 128);
#pragma unroll
  for (int kt = 0; kt < 4; ++kt) {
    bf16x8 af = *(const bf16x8*)(arow + ((unsigned)(kt * 64 + lkg * 16) ^ aswz));
#pragma unroll
    for (int jt = 0; jt < 4; ++jt)
      acc[jt] = __builtin_amdgcn_mfma_f32_16x16x32_bf16(af, wf[kt][jt],
                                                        acc[jt], 0, 0, 0);
  }

#pragma unroll
  for (int jt = 0; jt < 4; ++jt) {
    float bj = bias[jt * 16 + lrow];
#pragma unroll
    for (int r = 0; r < 4; ++r) {
      int n = node0 + lkg * 4 + r;
      if (n < n_nodes) out[n * DFEAT + jt * 16 + lrow] = acc[jt][r] + bj;
    }
  }
}

// ===========================================================================
// Last-resort fallback: atomic scatter + separate vector GEMM.
// ===========================================================================
__global__ __launch_bounds__(256) void gcn_scatter_kernel(
    const float4* __restrict__ feat4, const int* __restrict__ src,
    const int* __restrict__ dst, float* __restrict__ agg, int n_edges) {
  long long gid = (long long)blockIdx.x * blockDim.x + threadIdx.x;
  int e = (int)(gid >> 4);
  int c = (int)(gid & 15);
  if (e >= n_edges) return;
  float4 v = feat4[src[e] * 16 + c];
  float* p = agg + dst[e] * DFEAT + c * 4;
  atomicAdd(p + 0, v.x);
  atomicAdd(p + 1, v.y);
  atomicAdd(p + 2, v.z);
  atomicAdd(p + 3, v.w);
}

__global__ __launch_bounds__(256) void gcn_gemm_kernel(
    const float* __restrict__ feat, const float* __restrict__ agg,
    const float* __restrict__ W, const float* __restrict__ bias,
    float* __restrict__ out, int n_nodes) {
  __shared__ float4 Wl4[2048];
  __shared__ __align__(16) float hlf[16][128];
  int tid = threadIdx.x;
  for (int i = tid; i < 2048; i += 256) {
    int j = i >> 5, k4 = i & 31;
    Wl4[k4 * 64 + (j ^ (k4 & 7))] = ((const float4*)W)[i];
  }
  int node0 = blockIdx.x * 16;
  int wave = tid >> 6, lane = tid & 63;
  int mbase = wave * 4;
#pragma unroll
  for (int r = 0; r < 4; ++r) {
    int n = node0 + mbase + r;
    if (n < n_nodes) {
      hlf[mbase + r][lane]      = feat[n * DFEAT + lane];
      hlf[mbase + r][64 + lane] = agg[n * DFEAT + lane];
    }
  }
  __syncthreads();
  float a0 = 0.f, a1 = 0.f, a2 = 0.f, a3 = 0.f;
#pragma unroll 4
  for (int k4 = 0; k4 < 32; ++k4) {
    float4 w  = Wl4[k4 * 64 + (lane ^ (k4 & 7))];
    float4 h0 = *((const float4*)&hlf[mbase + 0][k4 * 4]);
    float4 h1 = *((const float4*)&hlf[mbase + 1][k4 * 4]);
    float4 h2 = *((const float4*)&hlf[mbase + 2][k4 * 4]);
    float4 h3 = *((const float4*)&hlf[mbase + 3][k4 * 4]);
    a0 += w.x * h0.x + w.y * h0.y + w.z * h0.z + w.w * h0.w;
    a1 += w.x * h1.x + w.y * h1.y + w.z * h1.z + w.w * h1.w;
    a2 += w.x * h2.x + w.y * h2.y + w.z * h2.z + w.w * h2.w;
    a3 += w.x * h3.x + w.y * h3.y + w.z * h3.z + w.w * h3.w;
  }
  float bj = bias[lane];
  int n = node0 + mbase;
  if (n + 0 < n_nodes) out[(n + 0) * DFEAT + lane] = a0 + bj;
  if (n + 1 < n_nodes) out[(n + 1) * DFEAT + lane] = a1 + bj;
  if (n + 2 < n_nodes) out[(n + 2) * DFEAT + lane] = a2 + bj;
  if (n + 3 < n_nodes) out[(n + 3) * DFEAT + lane] = a3 + bj;
}

// ===========================================================================

extern "C" void kernel_launch(void* const* d_in, const int* in_sizes, int n_in,
                              void* d_out, int out_size, void* d_ws, size_t ws_size,
                              hipStream_t stream) {
  const float* feat = (const float*)d_in[0];
  const int*   src  = (const int*)d_in[1];
  const int*   dst  = (const int*)d_in[2];
  const float* W    = (const float*)d_in[3];
  const float* bias = (const float*)d_in[4];
  float* out = (float*)d_out;

  int n_nodes = in_sizes[0] / DFEAT;   // 100000
  int n_edges = in_sizes[1];           // 1600000
  int nbkt = (n_nodes + BKSZ - 1) >> SB;   // 196

  auto align_up = [](size_t x) { return (x + 255) & ~(size_t)255; };
  size_t esrc_b = align_up((size_t)n_edges * 4);
  size_t off_b  = align_up((size_t)(n_nodes + 1) * 4);
  size_t bcnt_b = align_up((size_t)NBKT_PAD * 4);
  size_t bcur_b = align_up((size_t)NBKT_PAD * 4);
  size_t wb_b   = align_up((size_t)DFEAT * 128 * 2);
  size_t gb_b   = align_up((size_t)(n_nodes + 1) * DFEAT * 2);  // +sentinel row
  size_t need   = esrc_b + off_b + bcnt_b + bcur_b + wb_b + gb_b;

  bool pairs_fit = (size_t)out_size * 4 >= (size_t)n_edges * 8;
  bool ok = pairs_fit && nbkt >= 1 && nbkt <= NBKT_PAD && ws_size >= need;

  if (ok) {
    char* p = (char*)d_ws;
    int* edge_src = (int*)p;   p += esrc_b;
    int* offsets  = (int*)p;   p += off_b;
    int* bcnt     = (int*)p;   p += bcnt_b;
    int* bcur     = (int*)p;   p += bcur_b;
    unsigned short* wb = (unsigned short*)p;   p += wb_b;
    unsigned short* gb = (unsigned short*)p;
    int2* pairs = (int2*)d_out;                // dead before out is written

    hipMemsetAsync(bcnt, 0, bcnt_b + bcur_b, stream);   // bcnt + bcur

    int n4 = n_nodes * (DFEAT / 4);
    int nw4 = DFEAT * 128 / 4;
    gcn_prep<<<1024, 256, 0, stream>>>(
        (const float4*)feat, (ushort4*)gb, n4,
        (const float4*)W, (ushort4*)wb, nw4,
        dst, bcnt, n_edges, nbkt);

    int pblocks = (n_edges + PLACE_CHUNK - 1) / PLACE_CHUNK;
    gcn_place<<<pblocks, 256, 0, stream>>>(src, dst, bcnt, bcur, pairs,
                                           n_edges, nbkt);
    gcn_fillk<<<nbkt, 512, 0, stream>>>(pairs, bcnt, offsets, edge_src,
                                        n_nodes, n_edges, nbkt);

    int gblocks = (n_nodes + 63) / 64;
    gcn_gather_mfma<<<gblocks, 256, 0, stream>>>(
        (const ushort4*)gb, wb, edge_src, offsets, bias, out, n_nodes);
  } else {
    size_t agg_bytes = (size_t)n_nodes * DFEAT * sizeof(float);
    float* agg = (ws_size >= agg_bytes) ? (float*)d_ws : out;
    hipMemsetAsync(agg, 0, agg_bytes, stream);
    long long st = (long long)n_edges * 16;
    gcn_scatter_kernel<<<(int)((st + 255) / 256), 256, 0, stream>>>(
        (const float4*)feat, src, dst, agg, n_edges);
    int gblocks = (n_nodes + 15) / 16;
    gcn_gemm_kernel<<<gblocks, 256, 0, stream>>>(feat, agg, W, bias, out,
                                                 n_nodes);
  }
}